// Round 6
// baseline (1458.091 us; speedup 1.0000x reference)
//
#include <hip/hip_runtime.h>
#include <hip/hip_bf16.h>

typedef unsigned short u16;
typedef unsigned int   u32;
typedef _Float16 half2_t __attribute__((ext_vector_type(2)));
typedef short    bf16x8 __attribute__((ext_vector_type(8)));
typedef float    f32x4  __attribute__((ext_vector_type(4)));
typedef u32      u32x4v __attribute__((ext_vector_type(4)));

// Problem dims: B=128, T=512, V=50000, NT=24, E=128, H=256, Hd=128
#define TT   512

__device__ __forceinline__ float sigf(float x)  { return 1.0f / (1.0f + __expf(-x)); }
__device__ __forceinline__ float tanhf_(float x){ return 1.0f - 2.0f / (__expf(2.0f * x) + 1.0f); }

__device__ __forceinline__ u16 f2bf(float x) {
  __hip_bfloat16 h = __float2bfloat16(x);
  return *reinterpret_cast<u16*>(&h);
}
__device__ __forceinline__ float bf2f(u16 u) { return __uint_as_float(((u32)u) << 16); }
__device__ __forceinline__ u32 pk2(float a, float b) {
  return (u32)f2bf(a) | ((u32)f2bf(b) << 16);
}
__device__ __forceinline__ u16 f2h(float x) {
  _Float16 h = (_Float16)x;
  union { _Float16 f; u16 u; } c; c.f = h; return c.u;
}
__device__ __forceinline__ half2_t u2h2(u32 v) {
  union { u32 u; half2_t h; } c; c.u = v; return c.h;
}

// ---------------------------------------------------------------------------
// K0: weight prep. Wb bf16 [1024][128]; Whhb bf16 [2][512][128];
// bias f32 [1024]; Wout16 f16x2 [24][128].
// ---------------------------------------------------------------------------
__global__ __launch_bounds__(256) void prep_k(
    const float* __restrict__ Wih_f, const float* __restrict__ Wih_b,
    const float* __restrict__ Whh_f, const float* __restrict__ Whh_b,
    const float* __restrict__ bih_f, const float* __restrict__ bhh_f,
    const float* __restrict__ bih_b, const float* __restrict__ bhh_b,
    const float* __restrict__ W_out,
    u16* __restrict__ Wb, u16* __restrict__ Whhb, float* __restrict__ bias,
    u32* __restrict__ Wout16)
{
  int i = blockIdx.x * 256 + threadIdx.x;   // 131072 threads
  {
    int n = i >> 7, k = i & 127;
    float v = (n < 512) ? Wih_f[n * 128 + k] : Wih_b[(n - 512) * 128 + k];
    Wb[i] = f2bf(v);
  }
  {
    int d = i >> 16, rem = i & 65535, n = rem >> 7, k = rem & 127;
    const float* W = d ? Whh_b : Whh_f;
    Whhb[i] = f2bf(W[n * 128 + k]);
  }
  if (i < 1024) {
    int d = i >> 9, jj = i & 511;
    bias[i] = d ? (bih_b[jj] + bhh_b[jj]) : (bih_f[jj] + bhh_f[jj]);
  }
  if (i < 3072) {
    Wout16[i] = (u32)f2h(W_out[2 * i]) | ((u32)f2h(W_out[2 * i + 1]) << 16);
  }
}

// ---------------------------------------------------------------------------
// K1: embedding gather -> bf16 xe [65536][128]
// ---------------------------------------------------------------------------
__global__ __launch_bounds__(256) void embed_k(
    const int* __restrict__ x, const float* __restrict__ emb, u16* __restrict__ xe)
{
  const int tid = threadIdx.x;
  const int r = blockIdx.x * 8 + (tid >> 5);
  const int lane = tid & 31;
  int token = x[r];
  float4 v = *(const float4*)&emb[(size_t)token * 128 + lane * 4];
  uint2 p; p.x = pk2(v.x, v.y); p.y = pk2(v.z, v.w);
  *(uint2*)&xe[(size_t)r * 128 + lane * 4] = p;
}

// ---------------------------------------------------------------------------
// K2: gates GEMM via bf16 MFMA 16x16x32.  G[m][n] = sum_k xe[m][k]*Wb[n][k]+bias[n]
// ---------------------------------------------------------------------------
__global__ __launch_bounds__(256, 2) void gates_mfma_k(
    const u16* __restrict__ xe, const u16* __restrict__ Wb,
    const float* __restrict__ bias, u16* __restrict__ Gout)
{
  const int tid = threadIdx.x;
  const int wid = tid >> 6, l = tid & 63;
  const int wm = wid >> 1, wn = wid & 1;
  const int M0 = blockIdx.y * 128, N0 = blockIdx.x * 128;
  const int lr = l & 15, lk = l >> 4;

  f32x4 acc[4][4];
#pragma unroll
  for (int i = 0; i < 4; ++i)
#pragma unroll
    for (int j = 0; j < 4; ++j) acc[i][j] = (f32x4){0.f, 0.f, 0.f, 0.f};

#pragma unroll
  for (int ks = 0; ks < 4; ++ks) {
    bf16x8 a[4], b[4];
#pragma unroll
    for (int mi = 0; mi < 4; ++mi)
      a[mi] = *(const bf16x8*)&xe[(size_t)(M0 + wm * 64 + mi * 16 + lr) * 128 + ks * 32 + lk * 8];
#pragma unroll
    for (int ni = 0; ni < 4; ++ni)
      b[ni] = *(const bf16x8*)&Wb[(size_t)(N0 + wn * 64 + ni * 16 + lr) * 128 + ks * 32 + lk * 8];
#pragma unroll
    for (int mi = 0; mi < 4; ++mi)
#pragma unroll
      for (int ni = 0; ni < 4; ++ni)
        acc[mi][ni] = __builtin_amdgcn_mfma_f32_16x16x32_bf16(a[mi], b[ni], acc[mi][ni], 0, 0, 0);
  }

  float bcol[4];
#pragma unroll
  for (int ni = 0; ni < 4; ++ni) bcol[ni] = bias[N0 + wn * 64 + ni * 16 + lr];

  __shared__ u16 cs[128][136];
#pragma unroll
  for (int mi = 0; mi < 4; ++mi)
#pragma unroll
    for (int ni = 0; ni < 4; ++ni) {
      int col = wn * 64 + ni * 16 + lr;
#pragma unroll
      for (int r = 0; r < 4; ++r) {
        int row = wm * 64 + mi * 16 + lk * 4 + r;
        cs[row][col] = f2bf(acc[mi][ni][r] + bcol[ni]);
      }
    }
  __syncthreads();
  {
    int row = tid >> 1, c0 = (tid & 1) * 64;
    u16* dst = &Gout[(size_t)(M0 + row) * 1024 + N0 + c0];
#pragma unroll
    for (int q = 0; q < 8; ++q)
      *(uint4*)&dst[q * 8] = *(const uint4*)&cs[row][c0 + q * 8];
  }
}

// ---------------------------------------------------------------------------
// K3: LSTM recurrence via batched MFMA. 16 blocks = 2 dirs x 8 groups of 16
// samples; 512 threads = 8 waves, wave w owns output cols [w*64, w*64+64).
// Whh held as 16 bf16x8 B-fragments per thread (VGPR/AGPR resident — MFMA
// reads both). Per step: h(16x128 bf16, LDS) @ Whh^T via 16 MFMA; epilogue
// adds prefetched G preacts, activates, routes through LDS, updates c/h.
// ---------------------------------------------------------------------------
__global__ __launch_bounds__(512, 1) void lstm_mfma_k(
    const u16* __restrict__ G, const u16* __restrict__ Whhb,
    u16* __restrict__ Hout)
{
  const int bid = blockIdx.x;         // 0..15
  const int dir = bid & 1;
  const int grp = bid >> 1;           // 0..7 (16 samples each)
  const int tid = threadIdx.x;
  const int w = tid >> 6, l = tid & 63;
  const int lr = l & 15, lk = l >> 4;

  // B-fragments: Whh[n][k], n = w*64 + nt*16 + lr, k = ks*32 + lk*8
  const u16* wb = Whhb + ((size_t)dir << 16);
  bf16x8 B[16];
#pragma unroll
  for (int nt = 0; nt < 4; ++nt)
#pragma unroll
    for (int ks = 0; ks < 4; ++ks)
      B[nt * 4 + ks] = *(const bf16x8*)&wb[(size_t)(w * 64 + nt * 16 + lr) * 128 + ks * 32 + lk * 8];

  __shared__ u16  hlds[16][136];      // h as bf16, padded (272 B rows, 16B-aligned)
  __shared__ float gact[16][522];     // activated gates, padded stride

  for (int i = tid; i < 16 * 136; i += 512) ((u16*)hlds)[i] = 0;
  float cst0 = 0.f, cst1 = 0.f, cst2 = 0.f, cst3 = 0.f;

  const int ts = dir ? -1 : 1;
  int t = dir ? (TT - 1) : 0;
  const int bs_base = grp * 16 + lk * 4;     // sample row base for this lane
  const int colg = dir * 512 + w * 64;       // G column base for this wave

  u16 gcur[16], gnxt[16];
#pragma unroll
  for (int nt = 0; nt < 4; ++nt)
#pragma unroll
    for (int r = 0; r < 4; ++r)
      gcur[nt * 4 + r] = G[(size_t)((bs_base + r) * 512 + t) * 1024 + colg + nt * 16 + lr];
  __syncthreads();

  for (int step = 0; step < TT; ++step) {
    // prefetch next step's G preacts (hidden under this step's MFMA)
    if (step + 1 < TT) {
#pragma unroll
      for (int nt = 0; nt < 4; ++nt)
#pragma unroll
        for (int r = 0; r < 4; ++r)
          gnxt[nt * 4 + r] = G[(size_t)((bs_base + r) * 512 + (t + ts)) * 1024 + colg + nt * 16 + lr];
    }

    // A-fragments from h LDS
    bf16x8 A[4];
#pragma unroll
    for (int ks = 0; ks < 4; ++ks)
      A[ks] = *(const bf16x8*)&hlds[lr][ks * 32 + lk * 8];

    f32x4 acc[4];
#pragma unroll
    for (int nt = 0; nt < 4; ++nt) acc[nt] = (f32x4){0.f, 0.f, 0.f, 0.f};
#pragma unroll
    for (int ks = 0; ks < 4; ++ks)
#pragma unroll
      for (int nt = 0; nt < 4; ++nt)
        acc[nt] = __builtin_amdgcn_mfma_f32_16x16x32_bf16(A[ks], B[nt * 4 + ks], acc[nt], 0, 0, 0);

    // keep B-fragments loop-resident (VGPR or AGPR — MFMA reads either)
#define PIN(a,b,c,d) asm volatile("" : "+v"(a), "+v"(b), "+v"(c), "+v"(d));
    PIN(B[0], B[1], B[2], B[3])   PIN(B[4], B[5], B[6], B[7])
    PIN(B[8], B[9], B[10], B[11]) PIN(B[12], B[13], B[14], B[15])
#undef PIN

    // activations -> gact LDS
#pragma unroll
    for (int nt = 0; nt < 4; ++nt) {
      const int n = w * 64 + nt * 16 + lr;
      const int gate = n >> 7;           // wave-uniform per nt
#pragma unroll
      for (int r = 0; r < 4; ++r) {
        float g = acc[nt][r] + bf2f(gcur[nt * 4 + r]);
        float a = (gate == 2) ? tanhf_(g) : sigf(g);
        gact[lk * 4 + r][n] = a;
      }
    }
    __syncthreads();

    // c/h update: 4 hidden units per thread (idx = tid + r*512)
#pragma unroll
    for (int r = 0; r < 4; ++r) {
      int idx = tid + r * 512;
      int s = idx >> 7, u = idx & 127;
      float iv = gact[s][u], fv = gact[s][128 + u], gv = gact[s][256 + u], ov = gact[s][384 + u];
      float cv = (r == 0) ? cst0 : (r == 1) ? cst1 : (r == 2) ? cst2 : cst3;
      cv = fv * cv + iv * gv;
      float hv = ov * tanhf_(cv);
      if (r == 0) cst0 = cv; else if (r == 1) cst1 = cv; else if (r == 2) cst2 = cv; else cst3 = cv;
      hlds[s][u] = f2bf(hv);
      Hout[(size_t)((grp * 16 + s) * 512 + t) * 256 + dir * 128 + u] = f2h(hv);
    }
    __syncthreads();

#pragma unroll
    for (int i = 0; i < 16; ++i) gcur[i] = gnxt[i];
    t += ts;
  }
}

// ---------------------------------------------------------------------------
// K4: emissions = h @ W_out^T + b_out.  H f16, W_out f16-packed in LDS, fdot2.
// ---------------------------------------------------------------------------
__global__ __launch_bounds__(256) void emis_k(
    const u16* __restrict__ Hb, const u32* __restrict__ Wout16,
    const float* __restrict__ b_out, float* __restrict__ em)
{
  __shared__ __align__(16) u32 wl2[24 * 128];   // 12 KB
  __shared__ float bo[24];
  const int tid = threadIdx.x;
  for (int i = tid; i < 3072; i += 256) wl2[i] = Wout16[i];
  if (tid < 24) bo[tid] = b_out[tid];
  __syncthreads();

  const int m = blockIdx.x * 256 + tid;
  float acc[24];
#pragma unroll
  for (int tg = 0; tg < 24; ++tg) acc[tg] = bo[tg];

  const u32* h2 = (const u32*)(Hb + (size_t)m * 256);
  for (int ck = 0; ck < 16; ++ck) {          // 8 f16 per chunk
    uint4 hv = *(const uint4*)(h2 + ck * 4);
#pragma unroll
    for (int tg = 0; tg < 24; ++tg) {
      u32x4v wv = *(const u32x4v*)&wl2[tg * 128 + ck * 4];
      float a = acc[tg];
      a = __builtin_amdgcn_fdot2(u2h2(hv.x), u2h2(wv.x), a, false);
      a = __builtin_amdgcn_fdot2(u2h2(hv.y), u2h2(wv.y), a, false);
      a = __builtin_amdgcn_fdot2(u2h2(hv.z), u2h2(wv.z), a, false);
      a = __builtin_amdgcn_fdot2(u2h2(hv.w), u2h2(wv.w), a, false);
      acc[tg] = a;
    }
  }
#pragma unroll
  for (int t6 = 0; t6 < 6; ++t6) {
    float4 o;
    o.x = acc[t6*4+0]; o.y = acc[t6*4+1]; o.z = acc[t6*4+2]; o.w = acc[t6*4+3];
    *(float4*)&em[(size_t)m * 24 + t6 * 4] = o;
  }
}

// ---------------------------------------------------------------------------
// K5: CRF forward scan + gold score + mean. One wave per sample, all-register.
// ---------------------------------------------------------------------------
__device__ __forceinline__ int get_mask(const void* mp, int idx, bool byte_mode) {
  return byte_mode ? (int)((const unsigned char*)mp)[idx] : ((const int*)mp)[idx];
}

__global__ __launch_bounds__(64) void crf_k(
    const float* __restrict__ em, const int* __restrict__ tags,
    const void* __restrict__ maskp, const float* __restrict__ trans,
    const float* __restrict__ start_tr, const float* __restrict__ end_tr,
    float* __restrict__ out)
{
  const int b = blockIdx.x;
  const int tid = threadIdx.x;
  const bool byte_mode = (*(const u32*)maskp != 1u);

  int cnt = 0;
  for (int t = tid; t < TT; t += 64) cnt += get_mask(maskp, b * TT + t, byte_mode);
#pragma unroll
  for (int off = 32; off > 0; off >>= 1) cnt += __shfl_down(cnt, off);
  cnt = __shfl(cnt, 0);

  const bool act = (tid < 48);
  const int j  = (tid < 24) ? tid : tid - 24;
  const int i0 = (tid < 24) ? 0 : 12;
  const int partner = (tid < 24) ? tid + 24 : tid - 24;

  float tr_reg[12];
  if (act) {
#pragma unroll
    for (int k = 0; k < 12; ++k) tr_reg[k] = trans[(i0 + k) * 24 + j];
  }

  float sc = 0.f;
  if (act) sc = start_tr[j] + em[(size_t)(b * TT) * 24 + j];
  float em_next = 0.f;
  if (act && cnt > 1) em_next = em[(size_t)(b * TT + 1) * 24 + j];

  for (int t = 1; t < cnt; ++t) {
    float em_cur = em_next;
    if (act && t + 1 < cnt) em_next = em[(size_t)(b * TT + t + 1) * 24 + j];

    float v[12];
#pragma unroll
    for (int k = 0; k < 12; ++k) v[k] = __shfl(sc, i0 + k) + tr_reg[k];
    float mx = fmaxf(fmaxf(fmaxf(v[0], v[1]), fmaxf(v[2], v[3])),
                     fmaxf(fmaxf(v[4], v[5]), fmaxf(v[6], v[7])));
    mx = fmaxf(mx, fmaxf(fmaxf(v[8], v[9]), fmaxf(v[10], v[11])));
    float s = 0.f;
#pragma unroll
    for (int k = 0; k < 12; ++k) s += __expf(v[k] - mx);
    float mo = __shfl(mx, partner), so = __shfl(s, partner);
    float M = fmaxf(mx, mo);
    s = s * __expf(mx - M) + so * __expf(mo - M);
    sc = act ? (em_cur + M + __logf(s)) : 0.f;
  }

  float z = (tid < 24) ? sc + end_tr[tid] : -1e30f;
  float zm = z;
#pragma unroll
  for (int off = 32; off > 0; off >>= 1) zm = fmaxf(zm, __shfl_xor(zm, off));
  float ze = (tid < 24) ? __expf(z - zm) : 0.f;
#pragma unroll
  for (int off = 32; off > 0; off >>= 1) ze += __shfl_xor(ze, off);
  float lzv = zm + __logf(ze);

  float part = 0.f;
  for (int t = tid; t < TT; t += 64) {
    if (t >= 1 && t < cnt) {
      int tp = tags[b * TT + t - 1], tc = tags[b * TT + t];
      part += trans[tp * 24 + tc] + em[((size_t)(b * TT + t)) * 24 + tc];
    }
  }
#pragma unroll
  for (int off = 32; off > 0; off >>= 1) part += __shfl_down(part, off);
  if (tid == 0) {
    int t0g = tags[b * TT];
    float gold = start_tr[t0g] + em[(size_t)(b * TT) * 24 + t0g] + part;
    gold += end_tr[tags[b * TT + cnt - 1]];
    atomicAdd(out, (lzv - gold) * (1.0f / 128.0f));
  }
}

// ---------------------------------------------------------------------------
extern "C" void kernel_launch(void* const* d_in, const int* in_sizes, int n_in,
                              void* d_out, int out_size, void* d_ws, size_t ws_size,
                              hipStream_t stream) {
  const int*   x     = (const int*)d_in[0];
  const int*   tags  = (const int*)d_in[1];
  const void*  mask  = d_in[2];
  const float* emb   = (const float*)d_in[3];
  const float* Wih_f = (const float*)d_in[4];
  const float* Whh_f = (const float*)d_in[5];
  const float* bih_f = (const float*)d_in[6];
  const float* bhh_f = (const float*)d_in[7];
  const float* Wih_b = (const float*)d_in[8];
  const float* Whh_b = (const float*)d_in[9];
  const float* bih_b = (const float*)d_in[10];
  const float* bhh_b = (const float*)d_in[11];
  const float* W_out = (const float*)d_in[12];
  const float* b_out = (const float*)d_in[13];
  const float* trans = (const float*)d_in[14];
  const float* st_tr = (const float*)d_in[15];
  const float* en_tr = (const float*)d_in[16];

  u16*   Gb     = (u16*)d_ws;                              // [65536][1024] bf16
  u16*   Hb     = Gb + (size_t)65536 * 1024;               // [65536][256]  f16
  float* em     = (float*)(Hb + (size_t)65536 * 256);      // [65536][24]   f32
  float* bias   = em + (size_t)65536 * 24;                 // [1024]
  u16*   Wb     = (u16*)(bias + 1024);                     // [1024][128]   bf16
  u16*   Whhb   = Wb + 131072;                             // [2][512][128] bf16
  u32*   Wout16 = (u32*)(Whhb + 131072);                   // [24][128]     f16x2
  u16*   xe     = Hb;  // alias: xe dead before lstm writes Hb

  prep_k<<<512, 256, 0, stream>>>(Wih_f, Wih_b, Whh_f, Whh_b,
                                  bih_f, bhh_f, bih_b, bhh_b, W_out,
                                  Wb, Whhb, bias, Wout16);
  embed_k<<<8192, 256, 0, stream>>>(x, emb, xe);
  gates_mfma_k<<<dim3(8, 512), 256, 0, stream>>>(xe, Wb, bias, Gb);
  lstm_mfma_k<<<16, 512, 0, stream>>>(Gb, Whhb, Hb);
  emis_k<<<256, 256, 0, stream>>>(Hb, Wout16, b_out, em);
  hipMemsetAsync(d_out, 0, sizeof(float), stream);
  crf_k<<<128, 64, 0, stream>>>(em, tags, mask, trans, st_tr, en_tr, (float*)d_out);
}

// Round 8
// 1139.933 us; speedup vs baseline: 1.2791x; 1.2791x over previous
//
#include <hip/hip_runtime.h>
#include <hip/hip_bf16.h>

typedef unsigned short u16;
typedef unsigned int   u32;
typedef _Float16 half2_t __attribute__((ext_vector_type(2)));
typedef short    bf16x8 __attribute__((ext_vector_type(8)));
typedef float    f32x4  __attribute__((ext_vector_type(4)));
typedef u32      u32x4v __attribute__((ext_vector_type(4)));

// Problem dims: B=128, T=512, V=50000, NT=24, E=128, H=256, Hd=128
#define TT   512

__device__ __forceinline__ float sigf(float x)  { return 1.0f / (1.0f + __expf(-x)); }
__device__ __forceinline__ float tanhf_(float x){ return 1.0f - 2.0f / (__expf(2.0f * x) + 1.0f); }

__device__ __forceinline__ u16 f2bf(float x) {
  __hip_bfloat16 h = __float2bfloat16(x);
  return *reinterpret_cast<u16*>(&h);
}
__device__ __forceinline__ float bf2f(u16 u) { return __uint_as_float(((u32)u) << 16); }
__device__ __forceinline__ u32 pk2(float a, float b) {
  return (u32)f2bf(a) | ((u32)f2bf(b) << 16);
}
__device__ __forceinline__ u16 f2h(float x) {
  _Float16 h = (_Float16)x;
  union { _Float16 f; u16 u; } c; c.f = h; return c.u;
}
__device__ __forceinline__ half2_t u2h2(u32 v) {
  union { u32 u; half2_t h; } c; c.u = v; return c.h;
}

// ---------------------------------------------------------------------------
// K0: weight prep. Wb bf16 [1024][128]; Whhb bf16 [2][512][128];
// bias f32 [1024]; Wout16 f16x2 [24][128].
// ---------------------------------------------------------------------------
__global__ __launch_bounds__(256) void prep_k(
    const float* __restrict__ Wih_f, const float* __restrict__ Wih_b,
    const float* __restrict__ Whh_f, const float* __restrict__ Whh_b,
    const float* __restrict__ bih_f, const float* __restrict__ bhh_f,
    const float* __restrict__ bih_b, const float* __restrict__ bhh_b,
    const float* __restrict__ W_out,
    u16* __restrict__ Wb, u16* __restrict__ Whhb, float* __restrict__ bias,
    u32* __restrict__ Wout16)
{
  int i = blockIdx.x * 256 + threadIdx.x;   // 131072 threads
  {
    int n = i >> 7, k = i & 127;
    float v = (n < 512) ? Wih_f[n * 128 + k] : Wih_b[(n - 512) * 128 + k];
    Wb[i] = f2bf(v);
  }
  {
    int d = i >> 16, rem = i & 65535, n = rem >> 7, k = rem & 127;
    const float* W = d ? Whh_b : Whh_f;
    Whhb[i] = f2bf(W[n * 128 + k]);
  }
  if (i < 1024) {
    int d = i >> 9, jj = i & 511;
    bias[i] = d ? (bih_b[jj] + bhh_b[jj]) : (bih_f[jj] + bhh_f[jj]);
  }
  if (i < 3072) {
    Wout16[i] = (u32)f2h(W_out[2 * i]) | ((u32)f2h(W_out[2 * i + 1]) << 16);
  }
}

// ---------------------------------------------------------------------------
// K1: embedding gather -> bf16 xe [65536][128]
// ---------------------------------------------------------------------------
__global__ __launch_bounds__(256) void embed_k(
    const int* __restrict__ x, const float* __restrict__ emb, u16* __restrict__ xe)
{
  const int tid = threadIdx.x;
  const int r = blockIdx.x * 8 + (tid >> 5);
  const int lane = tid & 31;
  int token = x[r];
  float4 v = *(const float4*)&emb[(size_t)token * 128 + lane * 4];
  uint2 p; p.x = pk2(v.x, v.y); p.y = pk2(v.z, v.w);
  *(uint2*)&xe[(size_t)r * 128 + lane * 4] = p;
}

// ---------------------------------------------------------------------------
// K2: gates GEMM via bf16 MFMA 16x16x32.  G[m][n] = sum_k xe[m][k]*Wb[n][k]+bias[n]
// ---------------------------------------------------------------------------
__global__ __launch_bounds__(256, 2) void gates_mfma_k(
    const u16* __restrict__ xe, const u16* __restrict__ Wb,
    const float* __restrict__ bias, u16* __restrict__ Gout)
{
  const int tid = threadIdx.x;
  const int wid = tid >> 6, l = tid & 63;
  const int wm = wid >> 1, wn = wid & 1;
  const int M0 = blockIdx.y * 128, N0 = blockIdx.x * 128;
  const int lr = l & 15, lk = l >> 4;

  f32x4 acc[4][4];
#pragma unroll
  for (int i = 0; i < 4; ++i)
#pragma unroll
    for (int j = 0; j < 4; ++j) acc[i][j] = (f32x4){0.f, 0.f, 0.f, 0.f};

#pragma unroll
  for (int ks = 0; ks < 4; ++ks) {
    bf16x8 a[4], b[4];
#pragma unroll
    for (int mi = 0; mi < 4; ++mi)
      a[mi] = *(const bf16x8*)&xe[(size_t)(M0 + wm * 64 + mi * 16 + lr) * 128 + ks * 32 + lk * 8];
#pragma unroll
    for (int ni = 0; ni < 4; ++ni)
      b[ni] = *(const bf16x8*)&Wb[(size_t)(N0 + wn * 64 + ni * 16 + lr) * 128 + ks * 32 + lk * 8];
#pragma unroll
    for (int mi = 0; mi < 4; ++mi)
#pragma unroll
      for (int ni = 0; ni < 4; ++ni)
        acc[mi][ni] = __builtin_amdgcn_mfma_f32_16x16x32_bf16(a[mi], b[ni], acc[mi][ni], 0, 0, 0);
  }

  float bcol[4];
#pragma unroll
  for (int ni = 0; ni < 4; ++ni) bcol[ni] = bias[N0 + wn * 64 + ni * 16 + lr];

  __shared__ u16 cs[128][136];
#pragma unroll
  for (int mi = 0; mi < 4; ++mi)
#pragma unroll
    for (int ni = 0; ni < 4; ++ni) {
      int col = wn * 64 + ni * 16 + lr;
#pragma unroll
      for (int r = 0; r < 4; ++r) {
        int row = wm * 64 + mi * 16 + lk * 4 + r;
        cs[row][col] = f2bf(acc[mi][ni][r] + bcol[ni]);
      }
    }
  __syncthreads();
  {
    int row = tid >> 1, c0 = (tid & 1) * 64;
    u16* dst = &Gout[(size_t)(M0 + row) * 1024 + N0 + c0];
#pragma unroll
    for (int q = 0; q < 8; ++q)
      *(uint4*)&dst[q * 8] = *(const uint4*)&cs[row][c0 + q * 8];
  }
}

// ---------------------------------------------------------------------------
// K3: LSTM recurrence via batched MFMA, v2 (macro-hygiene fixed).
// 16 blocks = 2 dirs x 8 groups of 16 samples; 512 threads = 8 waves.
// Wave w owns hidden units u in [16w,16w+16): computes ALL FOUR gates for
// those units -> c/h update is thread-local (no gact LDS).
// G preact tile (16 samples x 512 cols) staged coalesced into
// double-buffered LDS one step ahead. h double-buffered -> 1 barrier/step.
// ---------------------------------------------------------------------------
__global__ __launch_bounds__(512, 1) void lstm_mfma_k(
    const u16* __restrict__ G, const u16* __restrict__ Whhb,
    u16* __restrict__ Hout)
{
  const int bid = blockIdx.x;         // 0..15
  const int dir = bid & 1;
  const int grp = bid >> 1;           // 0..7
  const int tid = threadIdx.x;
  const int w = tid >> 6, l = tid & 63;
  const int lr = l & 15, lk = l >> 4;
  const int u = 16 * w + lr;          // owned hidden unit column

  // B-fragments: gate g, k-slice ks:  Whh[n = g*128+u][k = ks*32+lk*8 ..+8]
  const u16* wbase = Whhb + ((size_t)dir << 16);
  bf16x8 B[4][4];
#pragma unroll
  for (int g = 0; g < 4; ++g)
#pragma unroll
    for (int ks = 0; ks < 4; ++ks)
      B[g][ks] = *(const bf16x8*)&wbase[(size_t)(g * 128 + u) * 128 + ks * 32 + lk * 8];

  __shared__ u16 hl[2][16][136];      // h bf16, double buffer, 272B rows
  __shared__ u16 gs[2][16][536];      // G tile bf16, double buffer, padded

  for (int i = tid; i < 2 * 16 * 136; i += 512) ((u16*)hl)[i] = 0;

  float c0 = 0.f, c1 = 0.f, c2 = 0.f, c3 = 0.f;
  const int ts = dir ? -1 : 1;
  int t = dir ? (TT - 1) : 0;

  // coalesced staging: thread -> (sample row, 32B chunk)
  const int srow = tid >> 5, chk = tid & 31;
  const u16* gsrc = G + (size_t)(grp * 16 + srow) * 512 * 1024
                      + (size_t)dir * 512 + chk * 16;
  const size_t hbase0 = ((size_t)(grp * 16 + lk * 4) * 512) * 256 + dir * 128 + u;

  uint4 rA0, rA1, rB0, rB1;
  {
    const u16* s0 = gsrc + (size_t)t * 1024;
    rA0 = *(const uint4*)s0; rA1 = *(const uint4*)(s0 + 8);
    const u16* s1 = gsrc + (size_t)(t + ts) * 1024;
    rB0 = *(const uint4*)s1; rB1 = *(const uint4*)(s1 + 8);
    *(uint4*)&gs[0][srow][chk * 16]     = rA0;
    *(uint4*)&gs[0][srow][chk * 16 + 8] = rA1;
  }
  __syncthreads();

#define EPI(r, cc, gfr, HWp) { \
    float gi  = acc[0][r] + (gfr)[0]; \
    float gf_ = acc[1][r] + (gfr)[1]; \
    float gg  = acc[2][r] + (gfr)[2]; \
    float go  = acc[3][r] + (gfr)[3]; \
    float iv = sigf(gi), fv = sigf(gf_), gv = tanhf_(gg), ov = sigf(go); \
    cc = fv * cc + iv * gv; \
    float hv = ov * tanhf_(cc); \
    hl[HWp][lk * 4 + r][u] = f2bf(hv); \
    Hout[hbase0 + (size_t)(r) * (512 * 256) + (size_t)t * 256] = f2h(hv); }

#define STEP(s, CB, WB, HR, HW, RL0, RL1, RW0, RW1) { \
    if ((s) + 2 < TT) { \
      const u16* sp = gsrc + (size_t)(t + 2 * ts) * 1024; \
      RL0 = *(const uint4*)sp; RL1 = *(const uint4*)(sp + 8); \
    } \
    bf16x8 A[4]; \
    _Pragma("unroll") \
    for (int ks = 0; ks < 4; ++ks) \
      A[ks] = *(const bf16x8*)&hl[HR][lr][ks * 32 + lk * 8]; \
    float gf0[4], gf1[4], gf2[4], gf3[4]; \
    _Pragma("unroll") \
    for (int g = 0; g < 4; ++g) { \
      gf0[g] = bf2f(gs[CB][lk * 4 + 0][g * 128 + u]); \
      gf1[g] = bf2f(gs[CB][lk * 4 + 1][g * 128 + u]); \
      gf2[g] = bf2f(gs[CB][lk * 4 + 2][g * 128 + u]); \
      gf3[g] = bf2f(gs[CB][lk * 4 + 3][g * 128 + u]); \
    } \
    f32x4 acc[4]; \
    _Pragma("unroll") \
    for (int g = 0; g < 4; ++g) acc[g] = (f32x4){0.f, 0.f, 0.f, 0.f}; \
    _Pragma("unroll") \
    for (int ks = 0; ks < 4; ++ks) \
      _Pragma("unroll") \
      for (int g = 0; g < 4; ++g) \
        acc[g] = __builtin_amdgcn_mfma_f32_16x16x32_bf16(A[ks], B[g][ks], acc[g], 0, 0, 0); \
    EPI(0, c0, gf0, HW)  EPI(1, c1, gf1, HW)  EPI(2, c2, gf2, HW)  EPI(3, c3, gf3, HW) \
    if ((s) + 1 < TT) { \
      *(uint4*)&gs[WB][srow][chk * 16]     = RW0; \
      *(uint4*)&gs[WB][srow][chk * 16 + 8] = RW1; \
    } \
    __syncthreads(); \
    t += ts; }

  for (int s = 0; s < TT; s += 2) {
    STEP(s,     0, 1, 0, 1, rA0, rA1, rB0, rB1)
    STEP(s + 1, 1, 0, 1, 0, rB0, rB1, rA0, rA1)
  }
#undef STEP
#undef EPI
}

// ---------------------------------------------------------------------------
// K4: emissions = h @ W_out^T + b_out.  H f16, W_out f16-packed in LDS, fdot2.
// ---------------------------------------------------------------------------
__global__ __launch_bounds__(256) void emis_k(
    const u16* __restrict__ Hb, const u32* __restrict__ Wout16,
    const float* __restrict__ b_out, float* __restrict__ em)
{
  __shared__ __align__(16) u32 wl2[24 * 128];   // 12 KB
  __shared__ float bo[24];
  const int tid = threadIdx.x;
  for (int i = tid; i < 3072; i += 256) wl2[i] = Wout16[i];
  if (tid < 24) bo[tid] = b_out[tid];
  __syncthreads();

  const int m = blockIdx.x * 256 + tid;
  float acc[24];
#pragma unroll
  for (int tg = 0; tg < 24; ++tg) acc[tg] = bo[tg];

  const u32* h2 = (const u32*)(Hb + (size_t)m * 256);
  for (int ck = 0; ck < 16; ++ck) {          // 8 f16 per chunk
    uint4 hv = *(const uint4*)(h2 + ck * 4);
#pragma unroll
    for (int tg = 0; tg < 24; ++tg) {
      u32x4v wv = *(const u32x4v*)&wl2[tg * 128 + ck * 4];
      float a = acc[tg];
      a = __builtin_amdgcn_fdot2(u2h2(hv.x), u2h2(wv.x), a, false);
      a = __builtin_amdgcn_fdot2(u2h2(hv.y), u2h2(wv.y), a, false);
      a = __builtin_amdgcn_fdot2(u2h2(hv.z), u2h2(wv.z), a, false);
      a = __builtin_amdgcn_fdot2(u2h2(hv.w), u2h2(wv.w), a, false);
      acc[tg] = a;
    }
  }
#pragma unroll
  for (int t6 = 0; t6 < 6; ++t6) {
    float4 o;
    o.x = acc[t6*4+0]; o.y = acc[t6*4+1]; o.z = acc[t6*4+2]; o.w = acc[t6*4+3];
    *(float4*)&em[(size_t)m * 24 + t6 * 4] = o;
  }
}

// ---------------------------------------------------------------------------
// K5: CRF forward scan in PROBABILITY domain. One wave per sample.
// ---------------------------------------------------------------------------
__device__ __forceinline__ int get_mask(const void* mp, int idx, bool byte_mode) {
  return byte_mode ? (int)((const unsigned char*)mp)[idx] : ((const int*)mp)[idx];
}

__global__ __launch_bounds__(64) void crf_k(
    const float* __restrict__ em, const int* __restrict__ tags,
    const void* __restrict__ maskp, const float* __restrict__ trans,
    const float* __restrict__ start_tr, const float* __restrict__ end_tr,
    float* __restrict__ out)
{
  const int b = blockIdx.x;
  const int tid = threadIdx.x;
  const bool byte_mode = (*(const u32*)maskp != 1u);
  const bool act = (tid < 24);
  const int j = act ? tid : 0;

  int cnt = 0;
  for (int t = tid; t < TT; t += 64) cnt += get_mask(maskp, b * TT + t, byte_mode);
#pragma unroll
  for (int off = 32; off > 0; off >>= 1) cnt += __shfl_down(cnt, off);
  cnt = __shfl(cnt, 0);

  float Texp[24];
  if (act) {
#pragma unroll
    for (int i = 0; i < 24; ++i) Texp[i] = __expf(trans[i * 24 + j]);
  } else {
#pragma unroll
    for (int i = 0; i < 24; ++i) Texp[i] = 0.f;
  }

  float sc0 = act ? (start_tr[j] + em[(size_t)(b * TT) * 24 + j]) : -1e30f;
  float m = sc0;
#pragma unroll
  for (int off = 32; off > 0; off >>= 1) m = fmaxf(m, __shfl_xor(m, off));
  float P = act ? __expf(sc0 - m) : 0.f;
  float logC = m;

  __shared__ __align__(16) float Pl[32];
  float em_next = 0.f;
  if (act && cnt > 1) em_next = em[(size_t)(b * TT + 1) * 24 + j];

  for (int t = 1; t < cnt; ++t) {
    float em_cur = em_next;
    if (act && t + 1 < cnt) em_next = em[(size_t)(b * TT + t + 1) * 24 + j];

    if (act) Pl[tid] = P;
    __syncthreads();
    float4 p0 = *(const float4*)&Pl[0];
    float4 p1 = *(const float4*)&Pl[4];
    float4 p2 = *(const float4*)&Pl[8];
    float4 p3 = *(const float4*)&Pl[12];
    float4 p4 = *(const float4*)&Pl[16];
    float4 p5 = *(const float4*)&Pl[20];
    float s0 = p0.x * Texp[0] + p0.y * Texp[1] + p0.z * Texp[2] + p0.w * Texp[3];
    float s1 = p1.x * Texp[4] + p1.y * Texp[5] + p1.z * Texp[6] + p1.w * Texp[7];
    float s2 = p2.x * Texp[8] + p2.y * Texp[9] + p2.z * Texp[10] + p2.w * Texp[11];
    float s3 = p3.x * Texp[12] + p3.y * Texp[13] + p3.z * Texp[14] + p3.w * Texp[15];
    float s4 = p4.x * Texp[16] + p4.y * Texp[17] + p4.z * Texp[18] + p4.w * Texp[19];
    float s5 = p5.x * Texp[20] + p5.y * Texp[21] + p5.z * Texp[22] + p5.w * Texp[23];
    float s = ((s0 + s1) + (s2 + s3)) + (s4 + s5);
    P = act ? (__expf(em_cur) * s) : 0.f;
    __syncthreads();   // WAR: next iteration's Pl write vs this iteration's reads

    if ((t & 3) == 0) {      // renormalize every 4 steps
      float mm = P;
#pragma unroll
      for (int off = 32; off > 0; off >>= 1) mm = fmaxf(mm, __shfl_xor(mm, off));
      P = P / mm;
      logC += __logf(mm);
    }
  }

  float z = act ? P * __expf(end_tr[j]) : 0.f;
#pragma unroll
  for (int off = 32; off > 0; off >>= 1) z += __shfl_xor(z, off);
  float lzv = logC + __logf(z);

  float part = 0.f;
  for (int t = tid; t < TT; t += 64) {
    if (t >= 1 && t < cnt) {
      int tp = tags[b * TT + t - 1], tc = tags[b * TT + t];
      part += trans[tp * 24 + tc] + em[((size_t)(b * TT + t)) * 24 + tc];
    }
  }
#pragma unroll
  for (int off = 32; off > 0; off >>= 1) part += __shfl_down(part, off);
  if (tid == 0) {
    int t0g = tags[b * TT];
    float gold = start_tr[t0g] + em[(size_t)(b * TT) * 24 + t0g] + part;
    gold += end_tr[tags[b * TT + cnt - 1]];
    atomicAdd(out, (lzv - gold) * (1.0f / 128.0f));
  }
}

// ---------------------------------------------------------------------------
extern "C" void kernel_launch(void* const* d_in, const int* in_sizes, int n_in,
                              void* d_out, int out_size, void* d_ws, size_t ws_size,
                              hipStream_t stream) {
  const int*   x     = (const int*)d_in[0];
  const int*   tags  = (const int*)d_in[1];
  const void*  mask  = d_in[2];
  const float* emb   = (const float*)d_in[3];
  const float* Wih_f = (const float*)d_in[4];
  const float* Whh_f = (const float*)d_in[5];
  const float* bih_f = (const float*)d_in[6];
  const float* bhh_f = (const float*)d_in[7];
  const float* Wih_b = (const float*)d_in[8];
  const float* Whh_b = (const float*)d_in[9];
  const float* bih_b = (const float*)d_in[10];
  const float* bhh_b = (const float*)d_in[11];
  const float* W_out = (const float*)d_in[12];
  const float* b_out = (const float*)d_in[13];
  const float* trans = (const float*)d_in[14];
  const float* st_tr = (const float*)d_in[15];
  const float* en_tr = (const float*)d_in[16];

  u16*   Gb     = (u16*)d_ws;                              // [65536][1024] bf16
  u16*   Hb     = Gb + (size_t)65536 * 1024;               // [65536][256]  f16
  float* em     = (float*)(Hb + (size_t)65536 * 256);      // [65536][24]   f32
  float* bias   = em + (size_t)65536 * 24;                 // [1024]
  u16*   Wb     = (u16*)(bias + 1024);                     // [1024][128]   bf16
  u16*   Whhb   = Wb + 131072;                             // [2][512][128] bf16
  u32*   Wout16 = (u32*)(Whhb + 131072);                   // [24][128]     f16x2
  u16*   xe     = Hb;  // alias: xe dead before lstm writes Hb

  prep_k<<<512, 256, 0, stream>>>(Wih_f, Wih_b, Whh_f, Whh_b,
                                  bih_f, bhh_f, bih_b, bhh_b, W_out,
                                  Wb, Whhb, bias, Wout16);
  embed_k<<<8192, 256, 0, stream>>>(x, emb, xe);
  gates_mfma_k<<<dim3(8, 512), 256, 0, stream>>>(xe, Wb, bias, Gb);
  lstm_mfma_k<<<16, 512, 0, stream>>>(Gb, Whhb, Hb);
  emis_k<<<256, 256, 0, stream>>>(Hb, Wout16, b_out, em);
  (void)hipMemsetAsync(d_out, 0, sizeof(float), stream);
  crf_k<<<128, 64, 0, stream>>>(em, tags, mask, trans, st_tr, en_tr, (float*)d_out);
}

// Round 9
// 946.139 us; speedup vs baseline: 1.5411x; 1.2048x over previous
//
#include <hip/hip_runtime.h>
#include <hip/hip_bf16.h>

typedef unsigned short u16;
typedef unsigned int   u32;
typedef _Float16 half2_t __attribute__((ext_vector_type(2)));
typedef short    bf16x8 __attribute__((ext_vector_type(8)));
typedef float    f32x4  __attribute__((ext_vector_type(4)));
typedef u32      u32x4v __attribute__((ext_vector_type(4)));

// Problem dims: B=128, T=512, V=50000, NT=24, E=128, H=256, Hd=128
#define TT   512

__device__ __forceinline__ float sigf(float x)  { return 1.0f / (1.0f + __expf(-x)); }
__device__ __forceinline__ float tanhf_(float x){ return 1.0f - 2.0f / (__expf(2.0f * x) + 1.0f); }

__device__ __forceinline__ u16 f2bf(float x) {
  __hip_bfloat16 h = __float2bfloat16(x);
  return *reinterpret_cast<u16*>(&h);
}
__device__ __forceinline__ float bf2f(u16 u) { return __uint_as_float(((u32)u) << 16); }
__device__ __forceinline__ u32 pk2(float a, float b) {
  return (u32)f2bf(a) | ((u32)f2bf(b) << 16);
}
__device__ __forceinline__ u16 f2h(float x) {
  _Float16 h = (_Float16)x;
  union { _Float16 f; u16 u; } c; c.f = h; return c.u;
}
__device__ __forceinline__ half2_t u2h2(u32 v) {
  union { u32 u; half2_t h; } c; c.u = v; return c.h;
}

// ---------------------------------------------------------------------------
// K0: weight prep.
// Wb bf16 [1024][128] with PERMUTED rows: row n = dir*512 + u*4 + g maps to
//   source W_dir[g*128+u] -> K2's GEMM output G has gates interleaved per unit.
// bias f32 [1024] same permutation. Whhb bf16 [2][512][128] (original layout).
// Wout16 f16x2 [24][128].
// ---------------------------------------------------------------------------
__global__ __launch_bounds__(256) void prep_k(
    const float* __restrict__ Wih_f, const float* __restrict__ Wih_b,
    const float* __restrict__ Whh_f, const float* __restrict__ Whh_b,
    const float* __restrict__ bih_f, const float* __restrict__ bhh_f,
    const float* __restrict__ bih_b, const float* __restrict__ bhh_b,
    const float* __restrict__ W_out,
    u16* __restrict__ Wb, u16* __restrict__ Whhb, float* __restrict__ bias,
    u32* __restrict__ Wout16)
{
  int i = blockIdx.x * 256 + threadIdx.x;   // 131072 threads
  {
    int n = i >> 7, k = i & 127;
    int d = n >> 9, rem = n & 511, uu = rem >> 2, g = rem & 3;
    const float* W = d ? Wih_b : Wih_f;
    Wb[i] = f2bf(W[(g * 128 + uu) * 128 + k]);
  }
  {
    int d = i >> 16, rem = i & 65535, n = rem >> 7, k = rem & 127;
    const float* W = d ? Whh_b : Whh_f;
    Whhb[i] = f2bf(W[n * 128 + k]);
  }
  if (i < 1024) {
    int d = i >> 9, rem = i & 511, uu = rem >> 2, g = rem & 3;
    int src = g * 128 + uu;
    bias[i] = d ? (bih_b[src] + bhh_b[src]) : (bih_f[src] + bhh_f[src]);
  }
  if (i < 3072) {
    Wout16[i] = (u32)f2h(W_out[2 * i]) | ((u32)f2h(W_out[2 * i + 1]) << 16);
  }
}

// ---------------------------------------------------------------------------
// K1: embedding gather -> bf16 xe [65536][128]
// ---------------------------------------------------------------------------
__global__ __launch_bounds__(256) void embed_k(
    const int* __restrict__ x, const float* __restrict__ emb, u16* __restrict__ xe)
{
  const int tid = threadIdx.x;
  const int r = blockIdx.x * 8 + (tid >> 5);
  const int lane = tid & 31;
  int token = x[r];
  float4 v = *(const float4*)&emb[(size_t)token * 128 + lane * 4];
  uint2 p; p.x = pk2(v.x, v.y); p.y = pk2(v.z, v.w);
  *(uint2*)&xe[(size_t)r * 128 + lane * 4] = p;
}

// ---------------------------------------------------------------------------
// K2: gates GEMM via bf16 MFMA 16x16x32.  G[m][n] = sum_k xe[m][k]*Wb[n][k]+bias[n]
// (operates transparently in the permuted column space)
// ---------------------------------------------------------------------------
__global__ __launch_bounds__(256, 2) void gates_mfma_k(
    const u16* __restrict__ xe, const u16* __restrict__ Wb,
    const float* __restrict__ bias, u16* __restrict__ Gout)
{
  const int tid = threadIdx.x;
  const int wid = tid >> 6, l = tid & 63;
  const int wm = wid >> 1, wn = wid & 1;
  const int M0 = blockIdx.y * 128, N0 = blockIdx.x * 128;
  const int lr = l & 15, lk = l >> 4;

  f32x4 acc[4][4];
#pragma unroll
  for (int i = 0; i < 4; ++i)
#pragma unroll
    for (int j = 0; j < 4; ++j) acc[i][j] = (f32x4){0.f, 0.f, 0.f, 0.f};

#pragma unroll
  for (int ks = 0; ks < 4; ++ks) {
    bf16x8 a[4], b[4];
#pragma unroll
    for (int mi = 0; mi < 4; ++mi)
      a[mi] = *(const bf16x8*)&xe[(size_t)(M0 + wm * 64 + mi * 16 + lr) * 128 + ks * 32 + lk * 8];
#pragma unroll
    for (int ni = 0; ni < 4; ++ni)
      b[ni] = *(const bf16x8*)&Wb[(size_t)(N0 + wn * 64 + ni * 16 + lr) * 128 + ks * 32 + lk * 8];
#pragma unroll
    for (int mi = 0; mi < 4; ++mi)
#pragma unroll
      for (int ni = 0; ni < 4; ++ni)
        acc[mi][ni] = __builtin_amdgcn_mfma_f32_16x16x32_bf16(a[mi], b[ni], acc[mi][ni], 0, 0, 0);
  }

  float bcol[4];
#pragma unroll
  for (int ni = 0; ni < 4; ++ni) bcol[ni] = bias[N0 + wn * 64 + ni * 16 + lr];

  __shared__ u16 cs[128][136];
#pragma unroll
  for (int mi = 0; mi < 4; ++mi)
#pragma unroll
    for (int ni = 0; ni < 4; ++ni) {
      int col = wn * 64 + ni * 16 + lr;
#pragma unroll
      for (int r = 0; r < 4; ++r) {
        int row = wm * 64 + mi * 16 + lk * 4 + r;
        cs[row][col] = f2bf(acc[mi][ni][r] + bcol[ni]);
      }
    }
  __syncthreads();
  {
    int row = tid >> 1, c0 = (tid & 1) * 64;
    u16* dst = &Gout[(size_t)(M0 + row) * 1024 + N0 + c0];
#pragma unroll
    for (int q = 0; q < 8; ++q)
      *(uint4*)&dst[q * 8] = *(const uint4*)&cs[row][c0 + q * 8];
  }
}

// ---------------------------------------------------------------------------
// K3: LSTM recurrence via batched MFMA, v3.
// 32 blocks = 2 dirs x 16 groups of 8 samples; 512 threads = 8 waves.
// Wave w owns units [16w,16w+16) x 4 gates for the MFMA (B resident in regs).
// After MFMA, accs are redistributed through LDS (pg) so each thread owns
// exactly 2 LSTM cells -> trans work spread over all 64 lanes and 2x CUs.
// G preacts gate-interleaved (prep_k permutation) -> clean ds_read_b64.
// G tile double-buffered + prefetched; h double-buffered; 2 barriers/step.
// ---------------------------------------------------------------------------
__global__ __launch_bounds__(512, 1) void lstm_mfma_k(
    const u16* __restrict__ G, const u16* __restrict__ Whhb,
    u16* __restrict__ Hout)
{
  const int bid = blockIdx.x;         // 0..31
  const int dir = bid & 1;
  const int grp = bid >> 1;           // 0..15
  const int tid = threadIdx.x;
  const int w = tid >> 6, l = tid & 63;
  const int lr = l & 15, lk = l >> 4;
  const int u = 16 * w + lr;          // MFMA-owned unit column

  // B-fragments: gate g, k-slice ks: Whh[g*128+u][ks*32+lk*8 ..+8]
  const u16* wbase = Whhb + ((size_t)dir << 16);
  bf16x8 B[4][4];
#pragma unroll
  for (int g = 0; g < 4; ++g)
#pragma unroll
    for (int ks = 0; ks < 4; ++ks)
      B[g][ks] = *(const bf16x8*)&wbase[(size_t)(g * 128 + u) * 128 + ks * 32 + lk * 8];

  __shared__ u16   hl[2][16][136];    // h bf16, dbuf; rows 8..15 stay zero
  __shared__ u16   gs[2][8][520];     // G tile (gate-interleaved), dbuf
  __shared__ float pg[8][516];        // MFMA accs, gate-contiguous per unit

  for (int i = tid; i < 2 * 16 * 136; i += 512) ((u16*)hl)[i] = 0;

  // cell ownership: sample cs_ = tid>>6 (== w), units cu and cu+64
  const int cs_ = tid >> 6;
  const int cu  = tid & 63;
  float cc0 = 0.f, cc1 = 0.f;

  const int ts = dir ? -1 : 1;
  int t = dir ? (TT - 1) : 0;

  // staging: thread loads 8 u16 (16B) of its sample row
  const u16* gsrc = G + ((size_t)(grp * 8 + cs_) * 512) * 1024 + dir * 512 + cu * 8;
  u16* hout0 = Hout + ((size_t)((grp * 8 + cs_) * 512 + t)) * 256 + dir * 128 + cu;

  {
    uint4 s0v = *(const uint4*)(gsrc + (size_t)t * 1024);
    *(uint4*)&gs[0][cs_][cu * 8] = s0v;
  }
  uint4 stg = *(const uint4*)(gsrc + (size_t)(t + ts) * 1024);
  __syncthreads();

  for (int s = 0; s < TT; ++s) {
    const int cb = s & 1, wbuf = cb ^ 1;

    // MFMA: h(t) @ Whh^T
    bf16x8 A[4];
#pragma unroll
    for (int ks = 0; ks < 4; ++ks)
      A[ks] = *(const bf16x8*)&hl[cb][lr][ks * 32 + lk * 8];
    f32x4 acc[4];
#pragma unroll
    for (int g = 0; g < 4; ++g) acc[g] = (f32x4){0.f, 0.f, 0.f, 0.f};
#pragma unroll
    for (int ks = 0; ks < 4; ++ks)
#pragma unroll
      for (int g = 0; g < 4; ++g)
        acc[g] = __builtin_amdgcn_mfma_f32_16x16x32_bf16(A[ks], B[g][ks], acc[g], 0, 0, 0);

    // redistribute accs: rows 0..7 are real samples (lanes lk<2)
    if (lk < 2) {
#pragma unroll
      for (int r = 0; r < 4; ++r) {
        f32x4 tv = (f32x4){acc[0][r], acc[1][r], acc[2][r], acc[3][r]};
        *(f32x4*)&pg[lk * 4 + r][u * 4] = tv;
      }
    }

    // stage next G tile; prefetch the one after
    if (s + 1 < TT) *(uint4*)&gs[wbuf][cs_][cu * 8] = stg;
    if (s + 2 < TT) stg = *(const uint4*)(gsrc + (size_t)(t + 2 * ts) * 1024);
    __syncthreads();

    // per-cell epilogue: 2 cells per thread
    f32x4 a0 = *(const f32x4*)&pg[cs_][cu * 4];
    f32x4 a1 = *(const f32x4*)&pg[cs_][(cu + 64) * 4];
    ushort4 q0 = *(const ushort4*)&gs[cb][cs_][cu * 4];
    ushort4 q1 = *(const ushort4*)&gs[cb][cs_][(cu + 64) * 4];

    float gi0 = a0.x + bf2f(q0.x), gf0 = a0.y + bf2f(q0.y);
    float gg0 = a0.z + bf2f(q0.z), go0 = a0.w + bf2f(q0.w);
    float iv0 = sigf(gi0), fv0 = sigf(gf0), gv0 = tanhf_(gg0), ov0 = sigf(go0);
    cc0 = fv0 * cc0 + iv0 * gv0;
    float hv0 = ov0 * tanhf_(cc0);

    float gi1 = a1.x + bf2f(q1.x), gf1 = a1.y + bf2f(q1.y);
    float gg1 = a1.z + bf2f(q1.z), go1 = a1.w + bf2f(q1.w);
    float iv1 = sigf(gi1), fv1 = sigf(gf1), gv1 = tanhf_(gg1), ov1 = sigf(go1);
    cc1 = fv1 * cc1 + iv1 * gv1;
    float hv1 = ov1 * tanhf_(cc1);

    hl[wbuf][cs_][cu]      = f2bf(hv0);
    hl[wbuf][cs_][cu + 64] = f2bf(hv1);
    hout0[0]  = f2h(hv0);
    hout0[64] = f2h(hv1);
    hout0 += ts * 256;
    __syncthreads();
    t += ts;
  }
}

// ---------------------------------------------------------------------------
// K4: emissions = h @ W_out^T + b_out.  H f16, W_out f16-packed in LDS, fdot2.
// ---------------------------------------------------------------------------
__global__ __launch_bounds__(256) void emis_k(
    const u16* __restrict__ Hb, const u32* __restrict__ Wout16,
    const float* __restrict__ b_out, float* __restrict__ em)
{
  __shared__ __align__(16) u32 wl2[24 * 128];   // 12 KB
  __shared__ float bo[24];
  const int tid = threadIdx.x;
  for (int i = tid; i < 3072; i += 256) wl2[i] = Wout16[i];
  if (tid < 24) bo[tid] = b_out[tid];
  __syncthreads();

  const int m = blockIdx.x * 256 + tid;
  float acc[24];
#pragma unroll
  for (int tg = 0; tg < 24; ++tg) acc[tg] = bo[tg];

  const u32* h2 = (const u32*)(Hb + (size_t)m * 256);
  for (int ck = 0; ck < 16; ++ck) {          // 8 f16 per chunk
    uint4 hv = *(const uint4*)(h2 + ck * 4);
#pragma unroll
    for (int tg = 0; tg < 24; ++tg) {
      u32x4v wv = *(const u32x4v*)&wl2[tg * 128 + ck * 4];
      float a = acc[tg];
      a = __builtin_amdgcn_fdot2(u2h2(hv.x), u2h2(wv.x), a, false);
      a = __builtin_amdgcn_fdot2(u2h2(hv.y), u2h2(wv.y), a, false);
      a = __builtin_amdgcn_fdot2(u2h2(hv.z), u2h2(wv.z), a, false);
      a = __builtin_amdgcn_fdot2(u2h2(hv.w), u2h2(wv.w), a, false);
      acc[tg] = a;
    }
  }
#pragma unroll
  for (int t6 = 0; t6 < 6; ++t6) {
    float4 o;
    o.x = acc[t6*4+0]; o.y = acc[t6*4+1]; o.z = acc[t6*4+2]; o.w = acc[t6*4+3];
    *(float4*)&em[(size_t)m * 24 + t6 * 4] = o;
  }
}

// ---------------------------------------------------------------------------
// K5: CRF forward scan in PROBABILITY domain. One wave per sample.
// ---------------------------------------------------------------------------
__device__ __forceinline__ int get_mask(const void* mp, int idx, bool byte_mode) {
  return byte_mode ? (int)((const unsigned char*)mp)[idx] : ((const int*)mp)[idx];
}

__global__ __launch_bounds__(64) void crf_k(
    const float* __restrict__ em, const int* __restrict__ tags,
    const void* __restrict__ maskp, const float* __restrict__ trans,
    const float* __restrict__ start_tr, const float* __restrict__ end_tr,
    float* __restrict__ out)
{
  const int b = blockIdx.x;
  const int tid = threadIdx.x;
  const bool byte_mode = (*(const u32*)maskp != 1u);
  const bool act = (tid < 24);
  const int j = act ? tid : 0;

  int cnt = 0;
  for (int t = tid; t < TT; t += 64) cnt += get_mask(maskp, b * TT + t, byte_mode);
#pragma unroll
  for (int off = 32; off > 0; off >>= 1) cnt += __shfl_down(cnt, off);
  cnt = __shfl(cnt, 0);

  float Texp[24];
  if (act) {
#pragma unroll
    for (int i = 0; i < 24; ++i) Texp[i] = __expf(trans[i * 24 + j]);
  } else {
#pragma unroll
    for (int i = 0; i < 24; ++i) Texp[i] = 0.f;
  }

  float sc0 = act ? (start_tr[j] + em[(size_t)(b * TT) * 24 + j]) : -1e30f;
  float m = sc0;
#pragma unroll
  for (int off = 32; off > 0; off >>= 1) m = fmaxf(m, __shfl_xor(m, off));
  float P = act ? __expf(sc0 - m) : 0.f;
  float logC = m;

  __shared__ __align__(16) float Pl[32];
  float em_next = 0.f;
  if (act && cnt > 1) em_next = em[(size_t)(b * TT + 1) * 24 + j];

  for (int t = 1; t < cnt; ++t) {
    float em_cur = em_next;
    if (act && t + 1 < cnt) em_next = em[(size_t)(b * TT + t + 1) * 24 + j];

    if (act) Pl[tid] = P;
    __syncthreads();
    float4 p0 = *(const float4*)&Pl[0];
    float4 p1 = *(const float4*)&Pl[4];
    float4 p2 = *(const float4*)&Pl[8];
    float4 p3 = *(const float4*)&Pl[12];
    float4 p4 = *(const float4*)&Pl[16];
    float4 p5 = *(const float4*)&Pl[20];
    float s0 = p0.x * Texp[0] + p0.y * Texp[1] + p0.z * Texp[2] + p0.w * Texp[3];
    float s1 = p1.x * Texp[4] + p1.y * Texp[5] + p1.z * Texp[6] + p1.w * Texp[7];
    float s2 = p2.x * Texp[8] + p2.y * Texp[9] + p2.z * Texp[10] + p2.w * Texp[11];
    float s3 = p3.x * Texp[12] + p3.y * Texp[13] + p3.z * Texp[14] + p3.w * Texp[15];
    float s4 = p4.x * Texp[16] + p4.y * Texp[17] + p4.z * Texp[18] + p4.w * Texp[19];
    float s5 = p5.x * Texp[20] + p5.y * Texp[21] + p5.z * Texp[22] + p5.w * Texp[23];
    float s = ((s0 + s1) + (s2 + s3)) + (s4 + s5);
    P = act ? (__expf(em_cur) * s) : 0.f;
    __syncthreads();   // WAR: next iteration's Pl write vs this iteration's reads

    if ((t & 3) == 0) {      // renormalize every 4 steps
      float mm = P;
#pragma unroll
      for (int off = 32; off > 0; off >>= 1) mm = fmaxf(mm, __shfl_xor(mm, off));
      P = P / mm;
      logC += __logf(mm);
    }
  }

  float z = act ? P * __expf(end_tr[j]) : 0.f;
#pragma unroll
  for (int off = 32; off > 0; off >>= 1) z += __shfl_xor(z, off);
  float lzv = logC + __logf(z);

  float part = 0.f;
  for (int t = tid; t < TT; t += 64) {
    if (t >= 1 && t < cnt) {
      int tp = tags[b * TT + t - 1], tc = tags[b * TT + t];
      part += trans[tp * 24 + tc] + em[((size_t)(b * TT + t)) * 24 + tc];
    }
  }
#pragma unroll
  for (int off = 32; off > 0; off >>= 1) part += __shfl_down(part, off);
  if (tid == 0) {
    int t0g = tags[b * TT];
    float gold = start_tr[t0g] + em[(size_t)(b * TT) * 24 + t0g] + part;
    gold += end_tr[tags[b * TT + cnt - 1]];
    atomicAdd(out, (lzv - gold) * (1.0f / 128.0f));
  }
}

// ---------------------------------------------------------------------------
extern "C" void kernel_launch(void* const* d_in, const int* in_sizes, int n_in,
                              void* d_out, int out_size, void* d_ws, size_t ws_size,
                              hipStream_t stream) {
  const int*   x     = (const int*)d_in[0];
  const int*   tags  = (const int*)d_in[1];
  const void*  mask  = d_in[2];
  const float* emb   = (const float*)d_in[3];
  const float* Wih_f = (const float*)d_in[4];
  const float* Whh_f = (const float*)d_in[5];
  const float* bih_f = (const float*)d_in[6];
  const float* bhh_f = (const float*)d_in[7];
  const float* Wih_b = (const float*)d_in[8];
  const float* Whh_b = (const float*)d_in[9];
  const float* bih_b = (const float*)d_in[10];
  const float* bhh_b = (const float*)d_in[11];
  const float* W_out = (const float*)d_in[12];
  const float* b_out = (const float*)d_in[13];
  const float* trans = (const float*)d_in[14];
  const float* st_tr = (const float*)d_in[15];
  const float* en_tr = (const float*)d_in[16];

  u16*   Gb     = (u16*)d_ws;                              // [65536][1024] bf16
  u16*   Hb     = Gb + (size_t)65536 * 1024;               // [65536][256]  f16
  float* em     = (float*)(Hb + (size_t)65536 * 256);      // [65536][24]   f32
  float* bias   = em + (size_t)65536 * 24;                 // [1024]
  u16*   Wb     = (u16*)(bias + 1024);                     // [1024][128]   bf16
  u16*   Whhb   = Wb + 131072;                             // [2][512][128] bf16
  u32*   Wout16 = (u32*)(Whhb + 131072);                   // [24][128]     f16x2
  u16*   xe     = Hb;  // alias: xe dead before lstm writes Hb

  prep_k<<<512, 256, 0, stream>>>(Wih_f, Wih_b, Whh_f, Whh_b,
                                  bih_f, bhh_f, bih_b, bhh_b, W_out,
                                  Wb, Whhb, bias, Wout16);
  embed_k<<<8192, 256, 0, stream>>>(x, emb, xe);
  gates_mfma_k<<<dim3(8, 512), 256, 0, stream>>>(xe, Wb, bias, Gb);
  lstm_mfma_k<<<32, 512, 0, stream>>>(Gb, Whhb, Hb);
  emis_k<<<256, 256, 0, stream>>>(Hb, Wout16, b_out, em);
  (void)hipMemsetAsync(d_out, 0, sizeof(float), stream);
  crf_k<<<128, 64, 0, stream>>>(em, tags, mask, trans, st_tr, en_tr, (float*)d_out);
}

// Round 10
// 741.551 us; speedup vs baseline: 1.9663x; 1.2759x over previous
//
#include <hip/hip_runtime.h>
#include <hip/hip_bf16.h>

typedef unsigned short u16;
typedef unsigned int   u32;
typedef _Float16 half2_t __attribute__((ext_vector_type(2)));
typedef short    bf16x8 __attribute__((ext_vector_type(8)));
typedef float    f32x4  __attribute__((ext_vector_type(4)));
typedef u32      u32x4v __attribute__((ext_vector_type(4)));

// Problem dims: B=128, T=512, V=50000, NT=24, E=128, H=256, Hd=128
#define TT   512

__device__ __forceinline__ float sigf(float x)  { return 1.0f / (1.0f + __expf(-x)); }
__device__ __forceinline__ float tanhf_(float x){ return 1.0f - 2.0f / (__expf(2.0f * x) + 1.0f); }

__device__ __forceinline__ u16 f2bf(float x) {
  __hip_bfloat16 h = __float2bfloat16(x);
  return *reinterpret_cast<u16*>(&h);
}
__device__ __forceinline__ float bf2f(u16 u) { return __uint_as_float(((u32)u) << 16); }
__device__ __forceinline__ u32 pk2(float a, float b) {
  return (u32)f2bf(a) | ((u32)f2bf(b) << 16);
}
__device__ __forceinline__ u16 f2h(float x) {
  _Float16 h = (_Float16)x;
  union { _Float16 f; u16 u; } c; c.f = h; return c.u;
}
__device__ __forceinline__ half2_t u2h2(u32 v) {
  union { u32 u; half2_t h; } c; c.u = v; return c.h;
}

// ---------------------------------------------------------------------------
// K0: weight prep.
// Wb bf16 [1024][128] PERMUTED rows: row n = dir*512 + u*4 + g <- W_dir[g*128+u]
// bias f32 [1024] same permutation. Whhb bf16 [2][512][128]. Wout16 [24][128].
// ---------------------------------------------------------------------------
__global__ __launch_bounds__(256) void prep_k(
    const float* __restrict__ Wih_f, const float* __restrict__ Wih_b,
    const float* __restrict__ Whh_f, const float* __restrict__ Whh_b,
    const float* __restrict__ bih_f, const float* __restrict__ bhh_f,
    const float* __restrict__ bih_b, const float* __restrict__ bhh_b,
    const float* __restrict__ W_out,
    u16* __restrict__ Wb, u16* __restrict__ Whhb, float* __restrict__ bias,
    u32* __restrict__ Wout16)
{
  int i = blockIdx.x * 256 + threadIdx.x;   // 131072 threads
  {
    int n = i >> 7, k = i & 127;
    int d = n >> 9, rem = n & 511, uu = rem >> 2, g = rem & 3;
    const float* W = d ? Wih_b : Wih_f;
    Wb[i] = f2bf(W[(g * 128 + uu) * 128 + k]);
  }
  {
    int d = i >> 16, rem = i & 65535, n = rem >> 7, k = rem & 127;
    const float* W = d ? Whh_b : Whh_f;
    Whhb[i] = f2bf(W[n * 128 + k]);
  }
  if (i < 1024) {
    int d = i >> 9, rem = i & 511, uu = rem >> 2, g = rem & 3;
    int src = g * 128 + uu;
    bias[i] = d ? (bih_b[src] + bhh_b[src]) : (bih_f[src] + bhh_f[src]);
  }
  if (i < 3072) {
    Wout16[i] = (u32)f2h(W_out[2 * i]) | ((u32)f2h(W_out[2 * i + 1]) << 16);
  }
}

// ---------------------------------------------------------------------------
// K1: embedding gather -> bf16 xe [65536][128]
// ---------------------------------------------------------------------------
__global__ __launch_bounds__(256) void embed_k(
    const int* __restrict__ x, const float* __restrict__ emb, u16* __restrict__ xe)
{
  const int tid = threadIdx.x;
  const int r = blockIdx.x * 8 + (tid >> 5);
  const int lane = tid & 31;
  int token = x[r];
  float4 v = *(const float4*)&emb[(size_t)token * 128 + lane * 4];
  uint2 p; p.x = pk2(v.x, v.y); p.y = pk2(v.z, v.w);
  *(uint2*)&xe[(size_t)r * 128 + lane * 4] = p;
}

// ---------------------------------------------------------------------------
// K2: gates GEMM via bf16 MFMA 16x16x32 (permuted column space).
// ---------------------------------------------------------------------------
__global__ __launch_bounds__(256, 2) void gates_mfma_k(
    const u16* __restrict__ xe, const u16* __restrict__ Wb,
    const float* __restrict__ bias, u16* __restrict__ Gout)
{
  const int tid = threadIdx.x;
  const int wid = tid >> 6, l = tid & 63;
  const int wm = wid >> 1, wn = wid & 1;
  const int M0 = blockIdx.y * 128, N0 = blockIdx.x * 128;
  const int lr = l & 15, lk = l >> 4;

  f32x4 acc[4][4];
#pragma unroll
  for (int i = 0; i < 4; ++i)
#pragma unroll
    for (int j = 0; j < 4; ++j) acc[i][j] = (f32x4){0.f, 0.f, 0.f, 0.f};

#pragma unroll
  for (int ks = 0; ks < 4; ++ks) {
    bf16x8 a[4], b[4];
#pragma unroll
    for (int mi = 0; mi < 4; ++mi)
      a[mi] = *(const bf16x8*)&xe[(size_t)(M0 + wm * 64 + mi * 16 + lr) * 128 + ks * 32 + lk * 8];
#pragma unroll
    for (int ni = 0; ni < 4; ++ni)
      b[ni] = *(const bf16x8*)&Wb[(size_t)(N0 + wn * 64 + ni * 16 + lr) * 128 + ks * 32 + lk * 8];
#pragma unroll
    for (int mi = 0; mi < 4; ++mi)
#pragma unroll
      for (int ni = 0; ni < 4; ++ni)
        acc[mi][ni] = __builtin_amdgcn_mfma_f32_16x16x32_bf16(a[mi], b[ni], acc[mi][ni], 0, 0, 0);
  }

  float bcol[4];
#pragma unroll
  for (int ni = 0; ni < 4; ++ni) bcol[ni] = bias[N0 + wn * 64 + ni * 16 + lr];

  __shared__ u16 cs[128][136];
#pragma unroll
  for (int mi = 0; mi < 4; ++mi)
#pragma unroll
    for (int ni = 0; ni < 4; ++ni) {
      int col = wn * 64 + ni * 16 + lr;
#pragma unroll
      for (int r = 0; r < 4; ++r) {
        int row = wm * 64 + mi * 16 + lk * 4 + r;
        cs[row][col] = f2bf(acc[mi][ni][r] + bcol[ni]);
      }
    }
  __syncthreads();
  {
    int row = tid >> 1, c0 = (tid & 1) * 64;
    u16* dst = &Gout[(size_t)(M0 + row) * 1024 + N0 + c0];
#pragma unroll
    for (int q = 0; q < 8; ++q)
      *(uint4*)&dst[q * 8] = *(const uint4*)&cs[row][c0 + q * 8];
  }
}

// ---------------------------------------------------------------------------
// K3: LSTM recurrence via batched MFMA, v4.
// 64 blocks = 2 dirs x 32 groups of 4 samples; 512 threads = 8 waves.
// Wave w owns units [16w,16w+16) x 4 gates (B resident in regs).
// G preacts loaded DIRECTLY to registers (8 B/thread, coalesced) at the top
// of the step, so the MFMA phase covers the latency before the compiler's
// vmcnt(0) drain at barrier #1. Hout store for step s-1 also issued at top.
// No VMEM between barrier #1 and #2. pg redistributes accs; 1 cell/thread.
// ---------------------------------------------------------------------------
__global__ __launch_bounds__(512, 1) void lstm_mfma_k(
    const u16* __restrict__ G, const u16* __restrict__ Whhb,
    u16* __restrict__ Hout)
{
  const int bid = blockIdx.x;         // 0..63
  const int dir = bid & 1;
  const int grp = bid >> 1;           // 0..31 (4 samples each)
  const int tid = threadIdx.x;
  const int w = tid >> 6, l = tid & 63;
  const int lr = l & 15, lk = l >> 4;
  const int u = 16 * w + lr;          // MFMA-owned unit column

  // B-fragments: gate g, k-slice ks: Whh[g*128+u][ks*32+lk*8 ..+8]
  const u16* wbase = Whhb + ((size_t)dir << 16);
  bf16x8 B[4][4];
#pragma unroll
  for (int g = 0; g < 4; ++g)
#pragma unroll
    for (int ks = 0; ks < 4; ++ks)
      B[g][ks] = *(const bf16x8*)&wbase[(size_t)(g * 128 + u) * 128 + ks * 32 + lk * 8];

  __shared__ u16   hl[2][16][136];    // h bf16, dbuf; rows 4..15 stay zero
  __shared__ float pg[4][516];        // MFMA accs, gate-contiguous per unit

  for (int i = tid; i < 2 * 16 * 136; i += 512) ((u16*)hl)[i] = 0;

  // cell ownership: 1 cell per thread
  const int cs_ = tid >> 7;           // sample 0..3
  const int cu  = tid & 127;          // unit 0..127
  float cc = 0.f;

  const int ts = dir ? -1 : 1;
  const int t0 = dir ? (TT - 1) : 0;
  const long gstride = (long)ts * 1024;
  const long hstride = (long)ts * 256;

  const u16* gptr = G + ((size_t)(grp * 4 + cs_) * 512 + t0) * 1024 + dir * 512 + cu * 4;
  u16*       hptr = Hout + ((size_t)(grp * 4 + cs_) * 512 + t0) * 256 + dir * 128 + cu;

  u16 hprev = 0;
  __syncthreads();

  for (int s = 0; s < TT; ++s) {
    const int cb = s & 1, wb = cb ^ 1;

    // issue this step's G load (to regs) + previous step's H store EARLY:
    // the MFMA phase below covers their latency before barrier #1's drain.
    ushort4 q = *(const ushort4*)gptr;
    gptr += gstride;
    if (s > 0) { *hptr = hprev; hptr += hstride; }

    // MFMA: h(t) @ Whh^T
    bf16x8 A[4];
#pragma unroll
    for (int ks = 0; ks < 4; ++ks)
      A[ks] = *(const bf16x8*)&hl[cb][lr][ks * 32 + lk * 8];
    f32x4 acc[4];
#pragma unroll
    for (int g = 0; g < 4; ++g) acc[g] = (f32x4){0.f, 0.f, 0.f, 0.f};
#pragma unroll
    for (int ks = 0; ks < 4; ++ks)
#pragma unroll
      for (int g = 0; g < 4; ++g)
        acc[g] = __builtin_amdgcn_mfma_f32_16x16x32_bf16(A[ks], B[g][ks], acc[g], 0, 0, 0);

    // redistribute: real samples are C rows 0..3 (lanes lk==0)
    if (lk == 0) {
#pragma unroll
      for (int r = 0; r < 4; ++r) {
        f32x4 tv = (f32x4){acc[0][r], acc[1][r], acc[2][r], acc[3][r]};
        *(f32x4*)&pg[r][u * 4] = tv;
      }
    }
    __syncthreads();

    // per-cell epilogue (1 cell per thread), preacts from registers
    f32x4 a = *(const f32x4*)&pg[cs_][cu * 4];
    float gi = a.x + bf2f(q.x), gf = a.y + bf2f(q.y);
    float gg = a.z + bf2f(q.z), go = a.w + bf2f(q.w);
    float iv = sigf(gi), fv = sigf(gf), gv = tanhf_(gg), ov = sigf(go);
    cc = fv * cc + iv * gv;
    float hv = ov * tanhf_(cc);
    hl[wb][cs_][cu] = f2bf(hv);
    hprev = f2h(hv);
    __syncthreads();
  }
  *hptr = hprev;   // final step's h
}

// ---------------------------------------------------------------------------
// K4: emissions = h @ W_out^T + b_out.  H f16, W_out f16-packed in LDS, fdot2.
// ---------------------------------------------------------------------------
__global__ __launch_bounds__(256) void emis_k(
    const u16* __restrict__ Hb, const u32* __restrict__ Wout16,
    const float* __restrict__ b_out, float* __restrict__ em)
{
  __shared__ __align__(16) u32 wl2[24 * 128];   // 12 KB
  __shared__ float bo[24];
  const int tid = threadIdx.x;
  for (int i = tid; i < 3072; i += 256) wl2[i] = Wout16[i];
  if (tid < 24) bo[tid] = b_out[tid];
  __syncthreads();

  const int m = blockIdx.x * 256 + tid;
  float acc[24];
#pragma unroll
  for (int tg = 0; tg < 24; ++tg) acc[tg] = bo[tg];

  const u32* h2 = (const u32*)(Hb + (size_t)m * 256);
  for (int ck = 0; ck < 16; ++ck) {          // 8 f16 per chunk
    uint4 hv = *(const uint4*)(h2 + ck * 4);
#pragma unroll
    for (int tg = 0; tg < 24; ++tg) {
      u32x4v wv = *(const u32x4v*)&wl2[tg * 128 + ck * 4];
      float a = acc[tg];
      a = __builtin_amdgcn_fdot2(u2h2(hv.x), u2h2(wv.x), a, false);
      a = __builtin_amdgcn_fdot2(u2h2(hv.y), u2h2(wv.y), a, false);
      a = __builtin_amdgcn_fdot2(u2h2(hv.z), u2h2(wv.z), a, false);
      a = __builtin_amdgcn_fdot2(u2h2(hv.w), u2h2(wv.w), a, false);
      acc[tg] = a;
    }
  }
#pragma unroll
  for (int t6 = 0; t6 < 6; ++t6) {
    float4 o;
    o.x = acc[t6*4+0]; o.y = acc[t6*4+1]; o.z = acc[t6*4+2]; o.w = acc[t6*4+3];
    *(float4*)&em[(size_t)m * 24 + t6 * 4] = o;
  }
}

// ---------------------------------------------------------------------------
// K5: CRF forward scan, probability domain, ALL cross-lane via __shfl:
// no LDS, no barriers (so the per-step em prefetch is never barrier-drained).
// Lane pairs split the 24-term matvec (12 terms each); renorm every 4 steps.
// ---------------------------------------------------------------------------
__device__ __forceinline__ int get_mask(const void* mp, int idx, bool byte_mode) {
  return byte_mode ? (int)((const unsigned char*)mp)[idx] : ((const int*)mp)[idx];
}

__global__ __launch_bounds__(64) void crf_k(
    const float* __restrict__ em, const int* __restrict__ tags,
    const void* __restrict__ maskp, const float* __restrict__ trans,
    const float* __restrict__ start_tr, const float* __restrict__ end_tr,
    float* __restrict__ out)
{
  const int b = blockIdx.x;
  const int tid = threadIdx.x;
  const bool byte_mode = (*(const u32*)maskp != 1u);
  const bool act = (tid < 48);
  const int j  = (tid < 24) ? tid : (act ? tid - 24 : 0);
  const int i0 = (tid < 24) ? 0 : 12;
  const int partner = (tid < 24) ? tid + 24 : tid - 24;

  int cnt = 0;
  for (int t = tid; t < TT; t += 64) cnt += get_mask(maskp, b * TT + t, byte_mode);
#pragma unroll
  for (int off = 32; off > 0; off >>= 1) cnt += __shfl_down(cnt, off);
  cnt = __shfl(cnt, 0);

  float Texp[12];
  if (act) {
#pragma unroll
    for (int k = 0; k < 12; ++k) Texp[k] = __expf(trans[(i0 + k) * 24 + j]);
  } else {
#pragma unroll
    for (int k = 0; k < 12; ++k) Texp[k] = 0.f;
  }

  float sc0 = act ? (start_tr[j] + em[(size_t)(b * TT) * 24 + j]) : -1e30f;
  float m = sc0;
#pragma unroll
  for (int off = 32; off > 0; off >>= 1) m = fmaxf(m, __shfl_xor(m, off));
  float P = act ? __expf(sc0 - m) : 0.f;   // lanes 24..47 hold mirror of lane j
  float logC = m;

  float em_next = 0.f;
  if (act && cnt > 1) em_next = em[(size_t)(b * TT + 1) * 24 + j];

  for (int t = 1; t < cnt; ++t) {
    float em_cur = em_next;
    if (act && t + 1 < cnt) em_next = em[(size_t)(b * TT + t + 1) * 24 + j];

    float s0 = 0.f, s1 = 0.f, s2 = 0.f;
#pragma unroll
    for (int k = 0; k < 4; ++k)  s0 += __shfl(P, i0 + k)     * Texp[k];
#pragma unroll
    for (int k = 4; k < 8; ++k)  s1 += __shfl(P, i0 + k)     * Texp[k];
#pragma unroll
    for (int k = 8; k < 12; ++k) s2 += __shfl(P, i0 + k)     * Texp[k];
    float sh = (s0 + s1) + s2;
    float so = __shfl(sh, partner);
    float tot = sh + so;
    P = act ? (__expf(em_cur) * tot) : 0.f;

    if ((t & 3) == 0) {          // renormalize every 4 steps
      float mm = P;
#pragma unroll
      for (int off = 32; off > 0; off >>= 1) mm = fmaxf(mm, __shfl_xor(mm, off));
      P = P / mm;
      logC += __logf(mm);
    }
  }

  float z = (tid < 24) ? P * __expf(end_tr[tid]) : 0.f;
#pragma unroll
  for (int off = 32; off > 0; off >>= 1) z += __shfl_xor(z, off);
  float lzv = logC + __logf(z);

  float part = 0.f;
  for (int t = tid; t < TT; t += 64) {
    if (t >= 1 && t < cnt) {
      int tp = tags[b * TT + t - 1], tc = tags[b * TT + t];
      part += trans[tp * 24 + tc] + em[((size_t)(b * TT + t)) * 24 + tc];
    }
  }
#pragma unroll
  for (int off = 32; off > 0; off >>= 1) part += __shfl_down(part, off);
  if (tid == 0) {
    int t0g = tags[b * TT];
    float gold = start_tr[t0g] + em[(size_t)(b * TT) * 24 + t0g] + part;
    gold += end_tr[tags[b * TT + cnt - 1]];
    atomicAdd(out, (lzv - gold) * (1.0f / 128.0f));
  }
}

// ---------------------------------------------------------------------------
extern "C" void kernel_launch(void* const* d_in, const int* in_sizes, int n_in,
                              void* d_out, int out_size, void* d_ws, size_t ws_size,
                              hipStream_t stream) {
  const int*   x     = (const int*)d_in[0];
  const int*   tags  = (const int*)d_in[1];
  const void*  mask  = d_in[2];
  const float* emb   = (const float*)d_in[3];
  const float* Wih_f = (const float*)d_in[4];
  const float* Whh_f = (const float*)d_in[5];
  const float* bih_f = (const float*)d_in[6];
  const float* bhh_f = (const float*)d_in[7];
  const float* Wih_b = (const float*)d_in[8];
  const float* Whh_b = (const float*)d_in[9];
  const float* bih_b = (const float*)d_in[10];
  const float* bhh_b = (const float*)d_in[11];
  const float* W_out = (const float*)d_in[12];
  const float* b_out = (const float*)d_in[13];
  const float* trans = (const float*)d_in[14];
  const float* st_tr = (const float*)d_in[15];
  const float* en_tr = (const float*)d_in[16];

  u16*   Gb     = (u16*)d_ws;                              // [65536][1024] bf16
  u16*   Hb     = Gb + (size_t)65536 * 1024;               // [65536][256]  f16
  float* em     = (float*)(Hb + (size_t)65536 * 256);      // [65536][24]   f32
  float* bias   = em + (size_t)65536 * 24;                 // [1024]
  u16*   Wb     = (u16*)(bias + 1024);                     // [1024][128]   bf16
  u16*   Whhb   = Wb + 131072;                             // [2][512][128] bf16
  u32*   Wout16 = (u32*)(Whhb + 131072);                   // [24][128]     f16x2
  u16*   xe     = Hb;  // alias: xe dead before lstm writes Hb

  prep_k<<<512, 256, 0, stream>>>(Wih_f, Wih_b, Whh_f, Whh_b,
                                  bih_f, bhh_f, bih_b, bhh_b, W_out,
                                  Wb, Whhb, bias, Wout16);
  embed_k<<<8192, 256, 0, stream>>>(x, emb, xe);
  gates_mfma_k<<<dim3(8, 512), 256, 0, stream>>>(xe, Wb, bias, Gb);
  lstm_mfma_k<<<64, 512, 0, stream>>>(Gb, Whhb, Hb);
  emis_k<<<256, 256, 0, stream>>>(Hb, Wout16, b_out, em);
  (void)hipMemsetAsync(d_out, 0, sizeof(float), stream);
  crf_k<<<128, 64, 0, stream>>>(em, tags, mask, trans, st_tr, en_tr, (float*)d_out);
}

// Round 11
// 596.682 us; speedup vs baseline: 2.4437x; 1.2428x over previous
//
#include <hip/hip_runtime.h>
#include <hip/hip_bf16.h>

typedef unsigned short u16;
typedef unsigned int   u32;
typedef _Float16 half2_t __attribute__((ext_vector_type(2)));
typedef short    bf16x8 __attribute__((ext_vector_type(8)));
typedef float    f32x4  __attribute__((ext_vector_type(4)));
typedef u32      u32x4v __attribute__((ext_vector_type(4)));

// Problem dims: B=128, T=512, V=50000, NT=24, E=128, H=256, Hd=128
#define TT   512

__device__ __forceinline__ float sigf(float x)  { return 1.0f / (1.0f + __expf(-x)); }
__device__ __forceinline__ float tanhf_(float x){ return 1.0f - 2.0f / (__expf(2.0f * x) + 1.0f); }

__device__ __forceinline__ u16 f2bf(float x) {
  __hip_bfloat16 h = __float2bfloat16(x);
  return *reinterpret_cast<u16*>(&h);
}
__device__ __forceinline__ float bf2f(u16 u) { return __uint_as_float(((u32)u) << 16); }
__device__ __forceinline__ u32 pk2(float a, float b) {
  return (u32)f2bf(a) | ((u32)f2bf(b) << 16);
}
__device__ __forceinline__ u16 f2h(float x) {
  _Float16 h = (_Float16)x;
  union { _Float16 f; u16 u; } c; c.f = h; return c.u;
}
__device__ __forceinline__ half2_t u2h2(u32 v) {
  union { u32 u; half2_t h; } c; c.u = v; return c.h;
}

// ---------------------------------------------------------------------------
// K0: weight prep.
// Wb bf16 [1024][128] PERMUTED rows: row n = dir*512 + u*4 + g <- W_dir[g*128+u]
// bias f32 [1024] same permutation. Whhb bf16 [2][512][128]. Wout16 [24][128].
// ---------------------------------------------------------------------------
__global__ __launch_bounds__(256) void prep_k(
    const float* __restrict__ Wih_f, const float* __restrict__ Wih_b,
    const float* __restrict__ Whh_f, const float* __restrict__ Whh_b,
    const float* __restrict__ bih_f, const float* __restrict__ bhh_f,
    const float* __restrict__ bih_b, const float* __restrict__ bhh_b,
    const float* __restrict__ W_out,
    u16* __restrict__ Wb, u16* __restrict__ Whhb, float* __restrict__ bias,
    u32* __restrict__ Wout16)
{
  int i = blockIdx.x * 256 + threadIdx.x;   // 131072 threads
  {
    int n = i >> 7, k = i & 127;
    int d = n >> 9, rem = n & 511, uu = rem >> 2, g = rem & 3;
    const float* W = d ? Wih_b : Wih_f;
    Wb[i] = f2bf(W[(g * 128 + uu) * 128 + k]);
  }
  {
    int d = i >> 16, rem = i & 65535, n = rem >> 7, k = rem & 127;
    const float* W = d ? Whh_b : Whh_f;
    Whhb[i] = f2bf(W[n * 128 + k]);
  }
  if (i < 1024) {
    int d = i >> 9, rem = i & 511, uu = rem >> 2, g = rem & 3;
    int src = g * 128 + uu;
    bias[i] = d ? (bih_b[src] + bhh_b[src]) : (bih_f[src] + bhh_f[src]);
  }
  if (i < 3072) {
    Wout16[i] = (u32)f2h(W_out[2 * i]) | ((u32)f2h(W_out[2 * i + 1]) << 16);
  }
}

// ---------------------------------------------------------------------------
// K1: embedding gather -> bf16 xe [65536][128]
// ---------------------------------------------------------------------------
__global__ __launch_bounds__(256) void embed_k(
    const int* __restrict__ x, const float* __restrict__ emb, u16* __restrict__ xe)
{
  const int tid = threadIdx.x;
  const int r = blockIdx.x * 8 + (tid >> 5);
  const int lane = tid & 31;
  int token = x[r];
  float4 v = *(const float4*)&emb[(size_t)token * 128 + lane * 4];
  uint2 p; p.x = pk2(v.x, v.y); p.y = pk2(v.z, v.w);
  *(uint2*)&xe[(size_t)r * 128 + lane * 4] = p;
}

// ---------------------------------------------------------------------------
// K2: gates GEMM via bf16 MFMA 16x16x32 (permuted column space).
// ---------------------------------------------------------------------------
__global__ __launch_bounds__(256, 2) void gates_mfma_k(
    const u16* __restrict__ xe, const u16* __restrict__ Wb,
    const float* __restrict__ bias, u16* __restrict__ Gout)
{
  const int tid = threadIdx.x;
  const int wid = tid >> 6, l = tid & 63;
  const int wm = wid >> 1, wn = wid & 1;
  const int M0 = blockIdx.y * 128, N0 = blockIdx.x * 128;
  const int lr = l & 15, lk = l >> 4;

  f32x4 acc[4][4];
#pragma unroll
  for (int i = 0; i < 4; ++i)
#pragma unroll
    for (int j = 0; j < 4; ++j) acc[i][j] = (f32x4){0.f, 0.f, 0.f, 0.f};

#pragma unroll
  for (int ks = 0; ks < 4; ++ks) {
    bf16x8 a[4], b[4];
#pragma unroll
    for (int mi = 0; mi < 4; ++mi)
      a[mi] = *(const bf16x8*)&xe[(size_t)(M0 + wm * 64 + mi * 16 + lr) * 128 + ks * 32 + lk * 8];
#pragma unroll
    for (int ni = 0; ni < 4; ++ni)
      b[ni] = *(const bf16x8*)&Wb[(size_t)(N0 + wn * 64 + ni * 16 + lr) * 128 + ks * 32 + lk * 8];
#pragma unroll
    for (int mi = 0; mi < 4; ++mi)
#pragma unroll
      for (int ni = 0; ni < 4; ++ni)
        acc[mi][ni] = __builtin_amdgcn_mfma_f32_16x16x32_bf16(a[mi], b[ni], acc[mi][ni], 0, 0, 0);
  }

  float bcol[4];
#pragma unroll
  for (int ni = 0; ni < 4; ++ni) bcol[ni] = bias[N0 + wn * 64 + ni * 16 + lr];

  __shared__ u16 cs[128][136];
#pragma unroll
  for (int mi = 0; mi < 4; ++mi)
#pragma unroll
    for (int ni = 0; ni < 4; ++ni) {
      int col = wn * 64 + ni * 16 + lr;
#pragma unroll
      for (int r = 0; r < 4; ++r) {
        int row = wm * 64 + mi * 16 + lk * 4 + r;
        cs[row][col] = f2bf(acc[mi][ni][r] + bcol[ni]);
      }
    }
  __syncthreads();
  {
    int row = tid >> 1, c0 = (tid & 1) * 64;
    u16* dst = &Gout[(size_t)(M0 + row) * 1024 + N0 + c0];
#pragma unroll
    for (int q = 0; q < 8; ++q)
      *(uint4*)&dst[q * 8] = *(const uint4*)&cs[row][c0 + q * 8];
  }
}

// ---------------------------------------------------------------------------
// K3: LSTM recurrence via MFMA, v5: one block per (dir,sample) = 256 blocks.
// 512 threads = 8 waves; wave w owns units [16w,16w+16) x 4 gates.
// MFMA C layout (col=lane&15, row=(lane>>4)*4+reg) puts ALL FOUR gates of
// cell (sample0, unit 16w+lr) in lane (lk=0,lr) regs -> epilogue is fully
// in-register, no redistribution LDS, ONE barrier per step.
// G preacts (256 B/wave, coalesced) prefetched one step ahead in registers.
// ---------------------------------------------------------------------------
__global__ __launch_bounds__(512, 1) void lstm_mfma_k(
    const u16* __restrict__ G, const u16* __restrict__ Whhb,
    u16* __restrict__ Hout)
{
  const int bid = blockIdx.x;         // 0..255
  const int dir = bid >> 7;
  const int b   = bid & 127;
  const int tid = threadIdx.x;
  const int w = tid >> 6, l = tid & 63;
  const int lr = l & 15, lk = l >> 4;
  const int u = 16 * w + lr;          // owned unit column

  // B-fragments: gate g, k-slice ks: Whh[g*128+u][ks*32+lk*8 ..+8]
  const u16* wbase = Whhb + ((size_t)dir << 16);
  bf16x8 B[4][4];
#pragma unroll
  for (int g = 0; g < 4; ++g)
#pragma unroll
    for (int ks = 0; ks < 4; ++ks)
      B[g][ks] = *(const bf16x8*)&wbase[(size_t)(g * 128 + u) * 128 + ks * 32 + lk * 8];

  __shared__ u16 hl[2][16][136];      // h bf16, dbuf; rows 1..15 stay zero

  for (int i = tid; i < 2 * 16 * 136; i += 512) ((u16*)hl)[i] = 0;

  float cc = 0.f;                      // cell state (lanes lk==0 only)
  const int ts = dir ? -1 : 1;
  const int t0 = dir ? (TT - 1) : 0;
  const long gstride = (long)ts * 1024;
  const long hstride = (long)ts * 256;

  // owner-lane G address: preacts for unit u, gates 0..3 (8 B)
  const u16* gptr = G + ((size_t)b * 512 + t0) * 1024 + dir * 512 + u * 4;
  u16*       hptr = Hout + ((size_t)b * 512 + t0) * 256 + dir * 128 + u;

  ushort4 qcur = *(const ushort4*)gptr;
  gptr += gstride;
  u16 hprev = 0;
  __syncthreads();

  for (int s = 0; s < TT; ++s) {
    const int cb = s & 1, wb = cb ^ 1;

    // prefetch next step's preacts + store previous step's h EARLY:
    // covered by this step's MFMA+epilogue before the barrier drain.
    ushort4 qnext = qcur;
    if (s + 1 < TT) { qnext = *(const ushort4*)gptr; gptr += gstride; }
    if (s > 0)      { *hptr = hprev; hptr += hstride; }

    // MFMA: h(t) @ Whh^T  (A rows 1..15 are zero padding)
    bf16x8 A[4];
#pragma unroll
    for (int ks = 0; ks < 4; ++ks)
      A[ks] = *(const bf16x8*)&hl[cb][lr][ks * 32 + lk * 8];
    f32x4 acc[4];
#pragma unroll
    for (int g = 0; g < 4; ++g) acc[g] = (f32x4){0.f, 0.f, 0.f, 0.f};
#pragma unroll
    for (int ks = 0; ks < 4; ++ks)
#pragma unroll
      for (int g = 0; g < 4; ++g)
        acc[g] = __builtin_amdgcn_mfma_f32_16x16x32_bf16(A[ks], B[g][ks], acc[g], 0, 0, 0);

    // in-lane epilogue: lane (lk==0, lr) owns cell (sample, unit u); C row 0 = reg 0
    if (lk == 0) {
      float gi = acc[0][0] + bf2f(qcur.x);
      float gf = acc[1][0] + bf2f(qcur.y);
      float gg = acc[2][0] + bf2f(qcur.z);
      float go = acc[3][0] + bf2f(qcur.w);
      float iv = sigf(gi), fv = sigf(gf), gv = tanhf_(gg), ov = sigf(go);
      cc = fv * cc + iv * gv;
      float hv = ov * tanhf_(cc);
      hl[wb][0][u] = f2bf(hv);
      hprev = f2h(hv);
    }
    __syncthreads();
    qcur = qnext;
  }
  if (lk == 0) *hptr = hprev;   // final step's h
}

// ---------------------------------------------------------------------------
// K4: emissions = h @ W_out^T + b_out.  H f16, W_out f16-packed in LDS, fdot2.
// ---------------------------------------------------------------------------
__global__ __launch_bounds__(256) void emis_k(
    const u16* __restrict__ Hb, const u32* __restrict__ Wout16,
    const float* __restrict__ b_out, float* __restrict__ em)
{
  __shared__ __align__(16) u32 wl2[24 * 128];   // 12 KB
  __shared__ float bo[24];
  const int tid = threadIdx.x;
  for (int i = tid; i < 3072; i += 256) wl2[i] = Wout16[i];
  if (tid < 24) bo[tid] = b_out[tid];
  __syncthreads();

  const int m = blockIdx.x * 256 + tid;
  float acc[24];
#pragma unroll
  for (int tg = 0; tg < 24; ++tg) acc[tg] = bo[tg];

  const u32* h2 = (const u32*)(Hb + (size_t)m * 256);
  for (int ck = 0; ck < 16; ++ck) {          // 8 f16 per chunk
    uint4 hv = *(const uint4*)(h2 + ck * 4);
#pragma unroll
    for (int tg = 0; tg < 24; ++tg) {
      u32x4v wv = *(const u32x4v*)&wl2[tg * 128 + ck * 4];
      float a = acc[tg];
      a = __builtin_amdgcn_fdot2(u2h2(hv.x), u2h2(wv.x), a, false);
      a = __builtin_amdgcn_fdot2(u2h2(hv.y), u2h2(wv.y), a, false);
      a = __builtin_amdgcn_fdot2(u2h2(hv.z), u2h2(wv.z), a, false);
      a = __builtin_amdgcn_fdot2(u2h2(hv.w), u2h2(wv.w), a, false);
      acc[tg] = a;
    }
  }
#pragma unroll
  for (int t6 = 0; t6 < 6; ++t6) {
    float4 o;
    o.x = acc[t6*4+0]; o.y = acc[t6*4+1]; o.z = acc[t6*4+2]; o.w = acc[t6*4+3];
    *(float4*)&em[(size_t)m * 24 + t6 * 4] = o;
  }
}

// ---------------------------------------------------------------------------
// K5: CRF forward scan, probability domain, all cross-lane via __shfl.
// ---------------------------------------------------------------------------
__device__ __forceinline__ int get_mask(const void* mp, int idx, bool byte_mode) {
  return byte_mode ? (int)((const unsigned char*)mp)[idx] : ((const int*)mp)[idx];
}

__global__ __launch_bounds__(64) void crf_k(
    const float* __restrict__ em, const int* __restrict__ tags,
    const void* __restrict__ maskp, const float* __restrict__ trans,
    const float* __restrict__ start_tr, const float* __restrict__ end_tr,
    float* __restrict__ out)
{
  const int b = blockIdx.x;
  const int tid = threadIdx.x;
  const bool byte_mode = (*(const u32*)maskp != 1u);
  const bool act = (tid < 48);
  const int j  = (tid < 24) ? tid : (act ? tid - 24 : 0);
  const int i0 = (tid < 24) ? 0 : 12;
  const int partner = (tid < 24) ? tid + 24 : tid - 24;

  int cnt = 0;
  for (int t = tid; t < TT; t += 64) cnt += get_mask(maskp, b * TT + t, byte_mode);
#pragma unroll
  for (int off = 32; off > 0; off >>= 1) cnt += __shfl_down(cnt, off);
  cnt = __shfl(cnt, 0);

  float Texp[12];
  if (act) {
#pragma unroll
    for (int k = 0; k < 12; ++k) Texp[k] = __expf(trans[(i0 + k) * 24 + j]);
  } else {
#pragma unroll
    for (int k = 0; k < 12; ++k) Texp[k] = 0.f;
  }

  float sc0 = act ? (start_tr[j] + em[(size_t)(b * TT) * 24 + j]) : -1e30f;
  float m = sc0;
#pragma unroll
  for (int off = 32; off > 0; off >>= 1) m = fmaxf(m, __shfl_xor(m, off));
  float P = act ? __expf(sc0 - m) : 0.f;
  float logC = m;

  float em_next = 0.f;
  if (act && cnt > 1) em_next = em[(size_t)(b * TT + 1) * 24 + j];

  for (int t = 1; t < cnt; ++t) {
    float em_cur = em_next;
    if (act && t + 1 < cnt) em_next = em[(size_t)(b * TT + t + 1) * 24 + j];

    float s0 = 0.f, s1 = 0.f, s2 = 0.f;
#pragma unroll
    for (int k = 0; k < 4; ++k)  s0 += __shfl(P, i0 + k)     * Texp[k];
#pragma unroll
    for (int k = 4; k < 8; ++k)  s1 += __shfl(P, i0 + k)     * Texp[k];
#pragma unroll
    for (int k = 8; k < 12; ++k) s2 += __shfl(P, i0 + k)     * Texp[k];
    float sh = (s0 + s1) + s2;
    float so = __shfl(sh, partner);
    float tot = sh + so;
    P = act ? (__expf(em_cur) * tot) : 0.f;

    if ((t & 3) == 0) {          // renormalize every 4 steps
      float mm = P;
#pragma unroll
      for (int off = 32; off > 0; off >>= 1) mm = fmaxf(mm, __shfl_xor(mm, off));
      P = P / mm;
      logC += __logf(mm);
    }
  }

  float z = (tid < 24) ? P * __expf(end_tr[tid]) : 0.f;
#pragma unroll
  for (int off = 32; off > 0; off >>= 1) z += __shfl_xor(z, off);
  float lzv = logC + __logf(z);

  float part = 0.f;
  for (int t = tid; t < TT; t += 64) {
    if (t >= 1 && t < cnt) {
      int tp = tags[b * TT + t - 1], tc = tags[b * TT + t];
      part += trans[tp * 24 + tc] + em[((size_t)(b * TT + t)) * 24 + tc];
    }
  }
#pragma unroll
  for (int off = 32; off > 0; off >>= 1) part += __shfl_down(part, off);
  if (tid == 0) {
    int t0g = tags[b * TT];
    float gold = start_tr[t0g] + em[(size_t)(b * TT) * 24 + t0g] + part;
    gold += end_tr[tags[b * TT + cnt - 1]];
    atomicAdd(out, (lzv - gold) * (1.0f / 128.0f));
  }
}

// ---------------------------------------------------------------------------
extern "C" void kernel_launch(void* const* d_in, const int* in_sizes, int n_in,
                              void* d_out, int out_size, void* d_ws, size_t ws_size,
                              hipStream_t stream) {
  const int*   x     = (const int*)d_in[0];
  const int*   tags  = (const int*)d_in[1];
  const void*  mask  = d_in[2];
  const float* emb   = (const float*)d_in[3];
  const float* Wih_f = (const float*)d_in[4];
  const float* Whh_f = (const float*)d_in[5];
  const float* bih_f = (const float*)d_in[6];
  const float* bhh_f = (const float*)d_in[7];
  const float* Wih_b = (const float*)d_in[8];
  const float* Whh_b = (const float*)d_in[9];
  const float* bih_b = (const float*)d_in[10];
  const float* bhh_b = (const float*)d_in[11];
  const float* W_out = (const float*)d_in[12];
  const float* b_out = (const float*)d_in[13];
  const float* trans = (const float*)d_in[14];
  const float* st_tr = (const float*)d_in[15];
  const float* en_tr = (const float*)d_in[16];

  u16*   Gb     = (u16*)d_ws;                              // [65536][1024] bf16
  u16*   Hb     = Gb + (size_t)65536 * 1024;               // [65536][256]  f16
  float* em     = (float*)(Hb + (size_t)65536 * 256);      // [65536][24]   f32
  float* bias   = em + (size_t)65536 * 24;                 // [1024]
  u16*   Wb     = (u16*)(bias + 1024);                     // [1024][128]   bf16
  u16*   Whhb   = Wb + 131072;                             // [2][512][128] bf16
  u32*   Wout16 = (u32*)(Whhb + 131072);                   // [24][128]     f16x2
  u16*   xe     = Hb;  // alias: xe dead before lstm writes Hb

  prep_k<<<512, 256, 0, stream>>>(Wih_f, Wih_b, Whh_f, Whh_b,
                                  bih_f, bhh_f, bih_b, bhh_b, W_out,
                                  Wb, Whhb, bias, Wout16);
  embed_k<<<8192, 256, 0, stream>>>(x, emb, xe);
  gates_mfma_k<<<dim3(8, 512), 256, 0, stream>>>(xe, Wb, bias, Gb);
  lstm_mfma_k<<<256, 512, 0, stream>>>(Gb, Whhb, Hb);
  emis_k<<<256, 256, 0, stream>>>(Hb, Wout16, b_out, em);
  (void)hipMemsetAsync(d_out, 0, sizeof(float), stream);
  crf_k<<<128, 64, 0, stream>>>(em, tags, mask, trans, st_tr, en_tr, (float*)d_out);
}